// Round 1
// baseline (13291.420 us; speedup 1.0000x reference)
//
#include <hip/hip_runtime.h>
#include <math.h>

typedef unsigned short u16;

#define HH 128
#define WW 128
#define NPIX 65536  // 4*128*128 output pixels

// ---------------- quantize + space_to_depth of q into bf16 groups ----------
// input NCHW [4,128,256,256]; q same layout (fp32, to d_out);
// ygrp[g][pix][f] bf16, pix=(b*128+y)*128+x, f = (c%32)*4 + (h&1)*2 + (w&1), g=c/32
__global__ void quant_s2d_kernel(const float* __restrict__ inp,
                                 float* __restrict__ q,
                                 u16* __restrict__ ygrp) {
  int idx = blockIdx.x * 256 + threadIdx.x;            // 33,554,432 total
  int ww = idx & 255;
  int hh = (idx >> 8) & 255;
  int cc = (idx >> 16) & 127;
  int b  = idx >> 23;
  float v = rintf(inp[idx]);
  q[idx] = v;
  int g = cc >> 5;
  int f = ((cc & 31) << 2) | ((hh & 1) << 1) | (ww & 1);
  int y = hh >> 1, x = ww >> 1;
  size_t p = ((size_t)(b * HH + y) * WW + x) * 128 + f;
  // v is a small integer -> bf16 truncation of bits is exact
  ygrp[(size_t)g * NPIX * 128 + p] = (u16)(__float_as_uint(v) >> 16);
}

// ---------------- space_to_depth of condition -> h0 and c0 (NHWC fp32) -----
__global__ void s2d_cond_kernel(const float* __restrict__ cond,
                                float* __restrict__ h0,
                                float* __restrict__ c0) {
  int idx = blockIdx.x * 256 + threadIdx.x;            // 8,388,608 total
  int ww = idx & 255;
  int hh = (idx >> 8) & 255;
  int cc = (idx >> 16) & 31;
  int b  = idx >> 21;
  float v = cond[idx];
  int p = (cc << 2) | ((hh & 1) << 1) | (ww & 1);
  int y = hh >> 1, x = ww >> 1;
  size_t o = ((size_t)(b * HH + y) * WW + x) * 128 + p;
  h0[o] = v;
  c0[o] = v;
}

// ---------------- weight reorg kernels ------------------------------------
// lstm_w [512][256][3][3] -> Blstm [tap][ci][co'] , co' = f*4+gate, orig co = gate*128+f
__global__ void reorg_lstm_kernel(const float* __restrict__ w, float* __restrict__ o) {
  int idx = blockIdx.x * 256 + threadIdx.x;            // 9*256*512 = 1,179,648
  int co = idx & 511;
  int ci = (idx >> 9) & 255;
  int t  = idx >> 17;
  int f = co >> 2, gate = co & 3;
  int oc = gate * 128 + f;
  o[idx] = w[(size_t)(oc * 256 + ci) * 9 + t];
}
// w2 [256][256][3][3] -> [tap][ci][co]
__global__ void reorg_w2_kernel(const float* __restrict__ w, float* __restrict__ o) {
  int idx = blockIdx.x * 256 + threadIdx.x;            // 9*256*256 = 589,824
  int co = idx & 255;
  int ci = (idx >> 8) & 255;
  int t  = idx >> 16;
  o[idx] = w[(size_t)(co * 256 + ci) * 9 + t];
}
// w1 [256][256][1][1] -> [ci][co]
__global__ void reorg_w1_kernel(const float* __restrict__ w, float* __restrict__ o) {
  int idx = blockIdx.x * 256 + threadIdx.x;            // 65536
  int co = idx & 255, ci = idx >> 8;
  o[idx] = w[co * 256 + ci];
}
// w3 [256][256][1][1] -> [ci][co'] with co' = f*2+m, orig co = m*128+f
__global__ void reorg_w3_kernel(const float* __restrict__ w, float* __restrict__ o) {
  int idx = blockIdx.x * 256 + threadIdx.x;            // 65536
  int cp = idx & 255, ci = idx >> 8;
  int f = cp >> 1, m = cp & 1;
  o[idx] = w[(m * 128 + f) * 256 + ci];
}
__global__ void reorg_bias_kernel(const float* __restrict__ lb, const float* __restrict__ b1,
                                  const float* __restrict__ b2, const float* __restrict__ b3,
                                  float* __restrict__ ol, float* __restrict__ o1,
                                  float* __restrict__ o2, float* __restrict__ o3) {
  int t = blockIdx.x * 256 + threadIdx.x;              // launch 512
  if (t < 512) { int f = t >> 2, g = t & 3; ol[t] = lb[g * 128 + f]; }
  if (t < 256) {
    o1[t] = b1[t];
    o2[t] = b2[t];
    int f = t >> 1, m = t & 1;
    o3[t] = b3[m * 128 + f];
  }
}

// ---------------- GEMM-conv with fused epilogues ---------------------------
// A: [pix][256ch] from two 128-ch sources (type 0=f32, 1=bf16, 2=zeros),
//    3x3 taps via spatial shift with zero pad.  B: [K][NCOL] reorged weights.
// EPI 0: LSTM gate update (writes h_out=out0, c in/out=out1)
// EPI 1: lrelu -> out0 (NHWC, 256 ch)
// EPI 2: likelihood -> out0 (NCHW [4,512,128,128]), z from zsrc (bf16)
template <int TAPS, int NCOL, int EPI>
__global__ __launch_bounds__(256, 2)
void conv_gemm(const void* __restrict__ a0p, int a0t, int a0s,
               const void* __restrict__ a1p, int a1t, int a1s,
               const float* __restrict__ Bw, const float* __restrict__ bias,
               float* __restrict__ out0, float* __restrict__ out1,
               const u16* __restrict__ zsrc, int g) {
  __shared__ float As[32][68];   // [k-within-slab][pixel]
  __shared__ float Bs[32][68];   // [k-within-slab][col]
  const int tid = threadIdx.x;
  const int tn = tid & 15, tm = tid >> 4;
  const int cb = blockIdx.x;                 // column block
  const int pb = blockIdx.y;                 // 1024 pixel blocks
  const int b = pb >> 8, rem = pb & 255;
  const int y = rem >> 1, x0 = (rem & 1) * 64;

  float acc[4][4] = {{0.f}};
  const int KTOT = TAPS * 256;
  for (int k0 = 0; k0 < KTOT; k0 += 32) {
    int tap = k0 >> 8;
    int ci0 = k0 & 255;
    int dy = 0, dx = 0;
    if (TAPS == 9) { dy = tap / 3 - 1; dx = tap % 3 - 1; }
    const void* ap; int at, astr;
    if (ci0 < 128) { ap = a0p; at = a0t; astr = a0s; }
    else           { ap = a1p; at = a1t; astr = a1s; }
    const int cloc = (ci0 & 127) + ((tid & 7) << 2);
    const int lk = (tid & 7) << 2;
#pragma unroll
    for (int it = 0; it < 2; ++it) {
      int xl = (tid >> 3) + it * 32;
      int yy = y + dy;
      int xx = x0 + xl + dx;
      float v0 = 0.f, v1 = 0.f, v2 = 0.f, v3 = 0.f;
      if (at != 2 && (unsigned)yy < (unsigned)HH && (unsigned)xx < (unsigned)WW) {
        size_t pidx = (size_t)(b * HH + yy) * WW + xx;
        if (at == 0) {
          const float* fp = (const float*)ap + pidx * astr + cloc;
          float4 t4 = *(const float4*)fp;
          v0 = t4.x; v1 = t4.y; v2 = t4.z; v3 = t4.w;
        } else {
          const u16* bp = (const u16*)ap + pidx * astr + cloc;
          ushort4 u = *(const ushort4*)bp;
          v0 = __uint_as_float((unsigned)u.x << 16);
          v1 = __uint_as_float((unsigned)u.y << 16);
          v2 = __uint_as_float((unsigned)u.z << 16);
          v3 = __uint_as_float((unsigned)u.w << 16);
        }
      }
      As[lk + 0][xl] = v0;
      As[lk + 1][xl] = v1;
      As[lk + 2][xl] = v2;
      As[lk + 3][xl] = v3;
    }
#pragma unroll
    for (int it = 0; it < 2; ++it) {
      int kr = (tid >> 4) + it * 16;
      int cl = (tid & 15) << 2;
      float4 t4 = *(const float4*)(Bw + (size_t)(k0 + kr) * NCOL + cb * 64 + cl);
      *(float4*)&Bs[kr][cl] = t4;
    }
    __syncthreads();
#pragma unroll
    for (int k = 0; k < 32; ++k) {
      float4 av = *(const float4*)&As[k][tm << 2];
      float4 bv = *(const float4*)&Bs[k][tn << 2];
      acc[0][0] += av.x * bv.x; acc[0][1] += av.x * bv.y; acc[0][2] += av.x * bv.z; acc[0][3] += av.x * bv.w;
      acc[1][0] += av.y * bv.x; acc[1][1] += av.y * bv.y; acc[1][2] += av.y * bv.z; acc[1][3] += av.y * bv.w;
      acc[2][0] += av.z * bv.x; acc[2][1] += av.z * bv.y; acc[2][2] += av.z * bv.z; acc[2][3] += av.z * bv.w;
      acc[3][0] += av.w * bv.x; acc[3][1] += av.w * bv.y; acc[3][2] += av.w * bv.z; acc[3][3] += av.w * bv.w;
    }
    __syncthreads();
  }

  if (EPI == 0) {
    // cols of this thread = 4 gates of channel f
    const int f = cb * 16 + tn;
    const float bi0 = bias[f * 4 + 0], bi1 = bias[f * 4 + 1];
    const float bi2 = bias[f * 4 + 2], bi3 = bias[f * 4 + 3];
#pragma unroll
    for (int r = 0; r < 4; ++r) {
      int x = x0 + (tm << 2) + r;
      size_t p = ((size_t)(b * HH + y) * WW + x) * 128 + f;
      float ig = 1.f / (1.f + expf(-(acc[r][0] + bi0)));
      float fg = 1.f / (1.f + expf(-(acc[r][1] + bi1)));
      float og = 1.f / (1.f + expf(-(acc[r][2] + bi2)));
      float gg = tanhf(acc[r][3] + bi3);
      float cn = fg * out1[p] + ig * gg;
      out1[p] = cn;
      out0[p] = og * tanhf(cn);
    }
  } else if (EPI == 1) {
#pragma unroll
    for (int r = 0; r < 4; ++r) {
      int x = x0 + (tm << 2) + r;
      size_t p = ((size_t)(b * HH + y) * WW + x) * 256;
#pragma unroll
      for (int s = 0; s < 4; ++s) {
        int co = cb * 64 + (tn << 2) + s;
        float v = acc[r][s] + bias[co];
        out0[p + co] = (v >= 0.f) ? v : 0.01f * v;
      }
    }
  } else {
    const float INVS2 = 0.70710678118654752f;
#pragma unroll
    for (int r = 0; r < 4; ++r) {
      int x = x0 + (tm << 2) + r;
      size_t pz = ((size_t)(b * HH + y) * WW + x) * 128;
#pragma unroll
      for (int ff = 0; ff < 2; ++ff) {
        int f = cb * 32 + (tn << 1) + ff;
        float mean = acc[r][ff * 2 + 0] + bias[f * 2 + 0];
        float sc   = acc[r][ff * 2 + 1] + bias[f * 2 + 1];
        sc = fmaxf(sc, 0.11f);
        float z = __uint_as_float((unsigned)zsrc[pz + f] << 16);
        float up = 0.5f * (1.f + erff((z - mean + 0.5f) / sc * INVS2));
        float lo = 0.5f * (1.f + erff((z - mean - 0.5f) / sc * INVS2));
        out0[((size_t)(b * 512 + g * 128 + f) * HH + y) * WW + x] = fmaxf(up - lo, 1e-9f);
      }
    }
  }
}

// ---------------- host launch ----------------------------------------------
extern "C" void kernel_launch(void* const* d_in, const int* in_sizes, int n_in,
                              void* d_out, int out_size, void* d_ws, size_t ws_size,
                              hipStream_t stream) {
  const float* input  = (const float*)d_in[0];
  const float* cond   = (const float*)d_in[1];
  const float* lstm_w = (const float*)d_in[2];
  const float* lstm_b = (const float*)d_in[3];
  const float* w1 = (const float*)d_in[4];
  const float* b1 = (const float*)d_in[5];
  const float* w2 = (const float*)d_in[6];
  const float* b2 = (const float*)d_in[7];
  const float* w3 = (const float*)d_in[8];
  const float* b3 = (const float*)d_in[9];

  float* q   = (float*)d_out;
  float* lik = q + 33554432;

  char* ws = (char*)d_ws;
  const size_t MB = 1ull << 20;
  float* hA   = (float*)(ws + 0);            // 32 MiB [NPIX][128] f32
  float* hB   = (float*)(ws + 32 * MB);      // 32 MiB
  float* cbuf = (float*)(ws + 64 * MB);      // 32 MiB
  float* t1   = (float*)(ws + 96 * MB);      // 64 MiB [NPIX][256] f32
  float* t2   = (float*)(ws + 160 * MB);     // 64 MiB
  u16*  ygrp  = (u16*)(ws + 224 * MB);       // 64 MiB [4][NPIX][128] bf16
  float* Blstm = (float*)(ws + 288 * MB);                    // 4,718,592 B
  float* Bw1   = (float*)(ws + 288 * MB + 4718592);          //   262,144 B
  float* Bw2   = (float*)(ws + 288 * MB + 4980736);          // 2,359,296 B
  float* Bw3   = (float*)(ws + 288 * MB + 7340032);          //   262,144 B
  float* blo   = (float*)(ws + 288 * MB + 7602176);          // 2 KiB
  float* b1o   = blo + 512;
  float* b2o   = b1o + 256;
  float* b3o   = b2o + 256;

  quant_s2d_kernel<<<131072, 256, 0, stream>>>(input, q, ygrp);
  s2d_cond_kernel<<<32768, 256, 0, stream>>>(cond, hA, cbuf);
  reorg_lstm_kernel<<<4608, 256, 0, stream>>>(lstm_w, Blstm);
  reorg_w2_kernel<<<2304, 256, 0, stream>>>(w2, Bw2);
  reorg_w1_kernel<<<256, 256, 0, stream>>>(w1, Bw1);
  reorg_w3_kernel<<<256, 256, 0, stream>>>(w3, Bw3);
  reorg_bias_kernel<<<2, 256, 0, stream>>>(lstm_b, b1, b2, b3, blo, b1o, b2o, b3o);

  for (int g = 0; g < 4; ++g) {
    float* hin  = (g & 1) ? hB : hA;
    float* hout = (g & 1) ? hA : hB;
    const u16* yi = g ? (ygrp + (size_t)(g - 1) * NPIX * 128) : nullptr;
    int yit = g ? 1 : 2;   // bf16 or zeros
    const u16* zg = ygrp + (size_t)g * NPIX * 128;

    // ConvLSTM: conv3x3 [yi, h] -> 512 gates, fused LSTM update
    conv_gemm<9, 512, 0><<<dim3(8, 1024), 256, 0, stream>>>(
        (const void*)yi, yit, 128, (const void*)hin, 0, 128,
        Blstm, blo, hout, cbuf, nullptr, g);
    // w1 1x1: [h, yi] -> 256, lrelu
    conv_gemm<1, 256, 1><<<dim3(4, 1024), 256, 0, stream>>>(
        (const void*)hout, 0, 128, (const void*)yi, yit, 128,
        Bw1, b1o, t1, nullptr, nullptr, g);
    // w2 3x3: t1 -> 256, lrelu
    conv_gemm<9, 256, 1><<<dim3(4, 1024), 256, 0, stream>>>(
        (const void*)t1, 0, 256, (const void*)(t1 + 128), 0, 256,
        Bw2, b2o, t2, nullptr, nullptr, g);
    // w3 1x1 + likelihood
    conv_gemm<1, 256, 2><<<dim3(4, 1024), 256, 0, stream>>>(
        (const void*)t2, 0, 256, (const void*)(t2 + 128), 0, 256,
        Bw3, b3o, lik, nullptr, zg, g);
  }
}

// Round 2
// 5501.616 us; speedup vs baseline: 2.4159x; 2.4159x over previous
//
#include <hip/hip_runtime.h>
#include <math.h>

typedef unsigned short u16;
typedef __attribute__((ext_vector_type(8))) short bf16x8;
typedef __attribute__((ext_vector_type(4))) float f32x4;

#define P128 8652800    // elems of padded 128-ch plane: 4*130*130*128
#define P256 17305600   // elems of padded 256-ch plane

__device__ __forceinline__ u16 f2bf(float f) {
  unsigned u = __float_as_uint(f);
  unsigned r = u + 0x7fffu + ((u >> 16) & 1u);
  return (u16)(r >> 16);
}
__device__ __forceinline__ float bf2f(u16 h) {
  return __uint_as_float(((unsigned)h) << 16);
}
__device__ __forceinline__ void gl16(const u16* g, const u16* l) {
  __builtin_amdgcn_global_load_lds(
      (const __attribute__((address_space(1))) void*)g,
      (__attribute__((address_space(3))) void*)l, 16, 0, 0);
}

// ---------- quantize + s2d into padded bf16 group planes --------------------
__global__ void quant_s2d_kernel(const float* __restrict__ inp,
                                 float* __restrict__ q,
                                 u16* __restrict__ yghi) {
  int idx = blockIdx.x * 256 + threadIdx.x;   // 33,554,432
  int ww = idx & 255;
  int hh = (idx >> 8) & 255;
  int cc = (idx >> 16) & 127;
  int b  = idx >> 23;
  float v = rintf(inp[idx]);
  q[idx] = v;
  int g = cc >> 5;
  int f = ((cc & 31) << 2) | ((hh & 1) << 1) | (ww & 1);
  int y = hh >> 1, x = ww >> 1;
  int p = (b * 130 + y + 1) * 130 + 1 + x;
  yghi[g * P128 + p * 128 + f] = f2bf(v);   // small integer -> exact
}

// ---------- s2d of condition -> h0 hi/lo (padded) + c0 (compact fp32) -------
__global__ void s2d_cond_kernel(const float* __restrict__ cond,
                                u16* __restrict__ hhi, u16* __restrict__ hlo,
                                float* __restrict__ c0) {
  int idx = blockIdx.x * 256 + threadIdx.x;   // 8,388,608
  int ww = idx & 255;
  int hh = (idx >> 8) & 255;
  int cc = (idx >> 16) & 31;
  int b  = idx >> 21;
  float v = cond[idx];
  int ch = (cc << 2) | ((hh & 1) << 1) | (ww & 1);
  int y = hh >> 1, x = ww >> 1;
  int p = (b * 130 + y + 1) * 130 + 1 + x;
  u16 h = f2bf(v);
  hhi[p * 128 + ch] = h;
  hlo[p * 128 + ch] = f2bf(v - bf2f(h));
  c0[((b * 128 + y) * 128 + x) * 128 + ch] = v;
}

// ---------- weight split/reorg: to [c'][K] bf16 hi/lo -----------------------
__global__ void split_lstm_w(const float* __restrict__ w, u16* __restrict__ hi, u16* __restrict__ lo) {
  int idx = blockIdx.x * 256 + threadIdx.x;   // 512*2304
  int k = idx % 2304, c = idx / 2304;
  int tap = k >> 8, ci = k & 255;
  int gate = (c >> 4) & 3;
  int f = (c >> 7) * 32 + ((c >> 6) & 1) * 16 + (c & 15);
  float v = w[((gate * 128 + f) * 256 + ci) * 9 + tap];
  u16 h = f2bf(v); hi[idx] = h; lo[idx] = f2bf(v - bf2f(h));
}
__global__ void split_w2(const float* __restrict__ w, u16* __restrict__ hi, u16* __restrict__ lo) {
  int idx = blockIdx.x * 256 + threadIdx.x;   // 256*2304
  int k = idx % 2304, c = idx / 2304;
  int tap = k >> 8, ci = k & 255;
  float v = w[(c * 256 + ci) * 9 + tap];
  u16 h = f2bf(v); hi[idx] = h; lo[idx] = f2bf(v - bf2f(h));
}
__global__ void split_w1(const float* __restrict__ w, u16* __restrict__ hi, u16* __restrict__ lo) {
  int idx = blockIdx.x * 256 + threadIdx.x;   // 65536
  float v = w[idx];   // [c][ci] natural: idx = c*256+ci and w is [c][ci][1][1]
  u16 h = f2bf(v); hi[idx] = h; lo[idx] = f2bf(v - bf2f(h));
}
__global__ void split_w3(const float* __restrict__ w, u16* __restrict__ hi, u16* __restrict__ lo) {
  int idx = blockIdx.x * 256 + threadIdx.x;   // 65536
  int ci = idx & 255, c = idx >> 8;
  int m = (c >> 4) & 1;
  int f = (c >> 7) * 64 + ((c >> 6) & 1) * 32 + ((c >> 5) & 1) * 16 + (c & 15);
  float v = w[(m * 128 + f) * 256 + ci];
  u16 h = f2bf(v); hi[idx] = h; lo[idx] = f2bf(v - bf2f(h));
}
__global__ void make_biases(const float* __restrict__ lb, const float* __restrict__ b1,
                            const float* __restrict__ b2, const float* __restrict__ b3,
                            float* __restrict__ pl, float* __restrict__ p1,
                            float* __restrict__ p2, float* __restrict__ p3) {
  int t = blockIdx.x * 256 + threadIdx.x;     // launch 512
  if (t < 512) {
    int gate = (t >> 4) & 3;
    int f = (t >> 7) * 32 + ((t >> 6) & 1) * 16 + (t & 15);
    pl[t] = lb[gate * 128 + f];
  }
  if (t < 256) {
    p1[t] = b1[t];
    p2[t] = b2[t];
    int m = (t >> 4) & 1;
    int f = (t >> 7) * 64 + ((t >> 6) & 1) * 32 + ((t >> 5) & 1) * 16 + (t & 15);
    p3[t] = b3[m * 128 + f];
  }
}

// ---------- MFMA conv (bf16x3) with fused epilogues -------------------------
// A sources: two 128-ch-slab (hi,lo) plane pairs; pixel stride C elems.
// Block: 128 pixels (one x-row strip) x 128 cols. 4 waves 2x2.
// EPI 0: LSTM update (c_io read/write; h -> ohi/olo padded 128ch)
// EPI 1: lrelu -> ohi/olo (C=256 out, geometry ORS/OPAD)
// EPI 2: likelihood -> lik (NCHW), z from zsrc padded bf16 plane
template <int TAPS, int NCOL, int EPI>
__global__ __launch_bounds__(256, 2)
void conv_mfma(const u16* __restrict__ a0hi, const u16* __restrict__ a0lo,
               const u16* __restrict__ a1hi, const u16* __restrict__ a1lo,
               int C, int RS, int PAD,
               const u16* __restrict__ Whi, const u16* __restrict__ Wlo,
               const float* __restrict__ biasP,
               float* __restrict__ c_io,
               u16* __restrict__ ohi, u16* __restrict__ olo, int ORS, int OPAD,
               const u16* __restrict__ zsrc, float* __restrict__ lik, int g) {
  __shared__ __attribute__((aligned(16))) u16 lds[16384];  // Ahi|Alo|Bhi|Blo, 8KB each
  const int tid = threadIdx.x;
  const int lane = tid & 63, wid = tid >> 6;
  const int wm = wid >> 1, wn = wid & 1;
  const int fl = lane & 15, kq = lane >> 4;
  const int cb = blockIdx.x;
  const int strip = blockIdx.y;
  const int b = strip >> 7, y = strip & 127;
  const int KT = TAPS * 256;

  f32x4 acc[4][4] = {};

  const int apix = tid & 127, aq0 = tid >> 7;   // load-slot decomposition

  for (int s = 0; s < KT / 32; ++s) {
    int dy = 0, dx = 0;
    if (TAPS == 9) { int tap = s >> 3; dy = tap / 3 - 1; dx = tap % 3 - 1; }
    const int ci0 = (s & 7) * 32;
    const u16* ahi = (ci0 < 128) ? a0hi : a1hi;
    const u16* alo = (ci0 < 128) ? a0lo : a1lo;
    const int cib = ci0 & 127;
    const int origin = (b * RS + y + PAD) * RS + PAD + dy * RS + dx;
    {
      const int gp = (origin + apix) * C + cib + aq0 * 8;
      gl16(ahi + gp,      &lds[0 + wid * 512]);
      gl16(ahi + gp + 16, &lds[2048 + wid * 512]);
      gl16(alo + gp,      &lds[4096 + wid * 512]);
      gl16(alo + gp + 16, &lds[6144 + wid * 512]);
      const int wp = (cb * 128 + apix) * KT + s * 32 + aq0 * 8;
      gl16(Whi + wp,      &lds[8192 + wid * 512]);
      gl16(Whi + wp + 16, &lds[10240 + wid * 512]);
      gl16(Wlo + wp,      &lds[12288 + wid * 512]);
      gl16(Wlo + wp + 16, &lds[14336 + wid * 512]);
    }
    __syncthreads();   // compiler drains vmcnt before s_barrier

    bf16x8 Ah[4], Al[4], Bh[4], Bl[4];
    const int ar = kq * 1024 + (wm * 64 + fl) * 8;
    const int br = kq * 1024 + (wn * 64 + fl) * 8;
#pragma unroll
    for (int i = 0; i < 4; ++i) {
      Ah[i] = *(const bf16x8*)&lds[ar + i * 128];
      Al[i] = *(const bf16x8*)&lds[4096 + ar + i * 128];
      Bh[i] = *(const bf16x8*)&lds[8192 + br + i * 128];
      Bl[i] = *(const bf16x8*)&lds[12288 + br + i * 128];
    }
#pragma unroll
    for (int mi = 0; mi < 4; ++mi)
#pragma unroll
      for (int ni = 0; ni < 4; ++ni) {
        acc[mi][ni] = __builtin_amdgcn_mfma_f32_16x16x32_bf16(Ah[mi], Bh[ni], acc[mi][ni], 0, 0, 0);
        acc[mi][ni] = __builtin_amdgcn_mfma_f32_16x16x32_bf16(Ah[mi], Bl[ni], acc[mi][ni], 0, 0, 0);
        acc[mi][ni] = __builtin_amdgcn_mfma_f32_16x16x32_bf16(Al[mi], Bh[ni], acc[mi][ni], 0, 0, 0);
      }
    __syncthreads();
  }

  if (EPI == 0) {
    const int f = cb * 32 + wn * 16 + fl;
    float bi[4];
#pragma unroll
    for (int ni = 0; ni < 4; ++ni) bi[ni] = biasP[cb * 128 + wn * 64 + ni * 16 + fl];
#pragma unroll
    for (int mi = 0; mi < 4; ++mi)
#pragma unroll
      for (int r = 0; r < 4; ++r) {
        int x = wm * 64 + mi * 16 + kq * 4 + r;
        int ci = ((b * 128 + y) * 128 + x) * 128 + f;
        float ig = 1.f / (1.f + expf(-(acc[mi][0][r] + bi[0])));
        float fg = 1.f / (1.f + expf(-(acc[mi][1][r] + bi[1])));
        float og = 1.f / (1.f + expf(-(acc[mi][2][r] + bi[2])));
        float gg = tanhf(acc[mi][3][r] + bi[3]);
        float cn = fg * c_io[ci] + ig * gg;
        c_io[ci] = cn;
        float hv = og * tanhf(cn);
        int hx = ((b * 130 + y + 1) * 130 + 1 + x) * 128 + f;
        u16 hb = f2bf(hv);
        ohi[hx] = hb;
        olo[hx] = f2bf(hv - bf2f(hb));
      }
  } else if (EPI == 1) {
#pragma unroll
    for (int ni = 0; ni < 4; ++ni) {
      int c = cb * 128 + wn * 64 + ni * 16 + fl;
      float bv = biasP[c];
#pragma unroll
      for (int mi = 0; mi < 4; ++mi)
#pragma unroll
        for (int r = 0; r < 4; ++r) {
          int x = wm * 64 + mi * 16 + kq * 4 + r;
          float v = acc[mi][ni][r] + bv;
          v = (v >= 0.f) ? v : 0.01f * v;
          int oi = ((b * ORS + y + OPAD) * ORS + OPAD + x) * 256 + c;
          u16 hb = f2bf(v);
          ohi[oi] = hb;
          olo[oi] = f2bf(v - bf2f(hb));
        }
    }
  } else {
#pragma unroll
    for (int j = 0; j < 2; ++j) {
      int f = cb * 64 + wn * 32 + j * 16 + fl;
      float bm = biasP[cb * 128 + wn * 64 + j * 32 + fl];
      float bs = biasP[cb * 128 + wn * 64 + j * 32 + 16 + fl];
#pragma unroll
      for (int mi = 0; mi < 4; ++mi)
#pragma unroll
        for (int r = 0; r < 4; ++r) {
          int x = wm * 64 + mi * 16 + kq * 4 + r;
          float mean = acc[mi][2 * j][r] + bm;
          float sc = fmaxf(acc[mi][2 * j + 1][r] + bs, 0.11f);
          float z = bf2f(zsrc[((b * 130 + y + 1) * 130 + 1 + x) * 128 + f]);
          float is = 0.70710678118654752f / sc;
          float up = 0.5f * (1.f + erff((z - mean + 0.5f) * is));
          float lo_ = 0.5f * (1.f + erff((z - mean - 0.5f) * is));
          lik[((b * 512 + g * 128 + f) * 128 + y) * 128 + x] = fmaxf(up - lo_, 1e-9f);
        }
    }
  }
}

// ---------- host launch ------------------------------------------------------
extern "C" void kernel_launch(void* const* d_in, const int* in_sizes, int n_in,
                              void* d_out, int out_size, void* d_ws, size_t ws_size,
                              hipStream_t stream) {
  const float* input  = (const float*)d_in[0];
  const float* cond   = (const float*)d_in[1];
  const float* lstm_w = (const float*)d_in[2];
  const float* lstm_b = (const float*)d_in[3];
  const float* w1 = (const float*)d_in[4];
  const float* b1 = (const float*)d_in[5];
  const float* w2 = (const float*)d_in[6];
  const float* b2 = (const float*)d_in[7];
  const float* w3 = (const float*)d_in[8];
  const float* b3 = (const float*)d_in[9];

  float* q   = (float*)d_out;
  float* lik = q + 33554432;

  char* ws = (char*)d_ws;
  u16* Z     = (u16*)(ws + 0);             // zero plane (P128)
  u16* YG    = (u16*)(ws + 17305600);      // 4 x P128 hi planes
  u16* HAhi  = (u16*)(ws + 86528000);
  u16* HAlo  = (u16*)(ws + 103833600);
  u16* HBhi  = (u16*)(ws + 121139200);
  u16* HBlo  = (u16*)(ws + 138444800);
  u16* T1hi  = (u16*)(ws + 155750400);     // P256
  u16* T1lo  = (u16*)(ws + 190361600);
  u16* T2hi  = (u16*)(ws + 224972800);     // compact [65536][256]
  u16* T2lo  = (u16*)(ws + 258527232);
  float* cbuf = (float*)(ws + 292081664);  // compact fp32 [65536][128]
  u16* WLhi = (u16*)(ws + 325636096);
  u16* WLlo = (u16*)(ws + 327995392);
  u16* W2hi = (u16*)(ws + 330354688);
  u16* W2lo = (u16*)(ws + 331534336);
  u16* W1hi = (u16*)(ws + 332713984);
  u16* W1lo = (u16*)(ws + 332845056);
  u16* W3hi = (u16*)(ws + 332976128);
  u16* W3lo = (u16*)(ws + 333107200);
  float* PL = (float*)(ws + 333238272);
  float* P1 = PL + 512;
  float* P2 = P1 + 256;
  float* P3 = P2 + 256;

  // zero: zero-plane + all padded-halo activation planes (interiors rewritten below)
  hipMemsetAsync(ws, 0, 224972800, stream);

  quant_s2d_kernel<<<131072, 256, 0, stream>>>(input, q, YG);
  s2d_cond_kernel<<<32768, 256, 0, stream>>>(cond, HAhi, HAlo, cbuf);
  split_lstm_w<<<4608, 256, 0, stream>>>(lstm_w, WLhi, WLlo);
  split_w2<<<2304, 256, 0, stream>>>(w2, W2hi, W2lo);
  split_w1<<<256, 256, 0, stream>>>(w1, W1hi, W1lo);
  split_w3<<<256, 256, 0, stream>>>(w3, W3hi, W3lo);
  make_biases<<<2, 256, 0, stream>>>(lstm_b, b1, b2, b3, PL, P1, P2, P3);

  for (int g = 0; g < 4; ++g) {
    u16* hinhi  = (g & 1) ? HBhi : HAhi;
    u16* hinlo  = (g & 1) ? HBlo : HAlo;
    u16* houthi = (g & 1) ? HAhi : HBhi;
    u16* houtlo = (g & 1) ? HAlo : HBlo;
    const u16* yihi = g ? (YG + (size_t)(g - 1) * P128) : Z;
    const u16* yilo = Z;
    const u16* zg = YG + (size_t)g * P128;

    // ConvLSTM 3x3: [yi, h] -> 512 gate cols, fused LSTM update
    conv_mfma<9, 512, 0><<<dim3(4, 512), 256, 0, stream>>>(
        yihi, yilo, hinhi, hinlo, 128, 130, 1,
        WLhi, WLlo, PL, cbuf, houthi, houtlo, 0, 0, nullptr, nullptr, g);
    // w1 1x1: [h, yi] -> 256, lrelu -> t1 (padded)
    conv_mfma<1, 256, 1><<<dim3(2, 512), 256, 0, stream>>>(
        houthi, houtlo, yihi, yilo, 128, 130, 1,
        W1hi, W1lo, P1, nullptr, T1hi, T1lo, 130, 1, nullptr, nullptr, g);
    // w2 3x3: t1 -> 256, lrelu -> t2 (compact)
    conv_mfma<9, 256, 1><<<dim3(2, 512), 256, 0, stream>>>(
        T1hi, T1lo, T1hi + 128, T1lo + 128, 256, 130, 1,
        W2hi, W2lo, P2, nullptr, T2hi, T2lo, 128, 0, nullptr, nullptr, g);
    // w3 1x1 + likelihood
    conv_mfma<1, 256, 2><<<dim3(2, 512), 256, 0, stream>>>(
        T2hi, T2lo, T2hi + 128, T2lo + 128, 256, 128, 0,
        W3hi, W3lo, P3, nullptr, nullptr, nullptr, 0, 0, zg, lik, g);
  }
}

// Round 3
// 4378.679 us; speedup vs baseline: 3.0355x; 1.2565x over previous
//
#include <hip/hip_runtime.h>
#include <math.h>

typedef unsigned short u16;
typedef __attribute__((ext_vector_type(8))) short bf16x8;
typedef __attribute__((ext_vector_type(4))) float f32x4;

#define P128 8652800    // elems of padded 128-ch plane: 4*130*130*128
#define P256 17305600   // elems of padded 256-ch plane

__device__ __forceinline__ u16 f2bf(float f) {
  unsigned u = __float_as_uint(f);
  unsigned r = u + 0x7fffu + ((u >> 16) & 1u);
  return (u16)(r >> 16);
}
__device__ __forceinline__ float bf2f(u16 h) {
  return __uint_as_float(((unsigned)h) << 16);
}
__device__ __forceinline__ void gl16(const u16* g, const u16* l) {
  __builtin_amdgcn_global_load_lds(
      (const __attribute__((address_space(1))) void*)g,
      (__attribute__((address_space(3))) void*)l, 16, 0, 0);
}

// ---------- quantize + s2d into padded bf16 group planes --------------------
__global__ void quant_s2d_kernel(const float* __restrict__ inp,
                                 float* __restrict__ q,
                                 u16* __restrict__ yghi) {
  int idx = blockIdx.x * 256 + threadIdx.x;   // 33,554,432
  int ww = idx & 255;
  int hh = (idx >> 8) & 255;
  int cc = (idx >> 16) & 127;
  int b  = idx >> 23;
  float v = rintf(inp[idx]);
  q[idx] = v;
  int g = cc >> 5;
  int f = ((cc & 31) << 2) | ((hh & 1) << 1) | (ww & 1);
  int y = hh >> 1, x = ww >> 1;
  int p = (b * 130 + y + 1) * 130 + 1 + x;
  yghi[g * P128 + p * 128 + f] = f2bf(v);   // small integer -> exact
}

// ---------- s2d of condition -> h0 hi/lo (padded) + c0 (compact fp32) -------
__global__ void s2d_cond_kernel(const float* __restrict__ cond,
                                u16* __restrict__ hhi, u16* __restrict__ hlo,
                                float* __restrict__ c0) {
  int idx = blockIdx.x * 256 + threadIdx.x;   // 8,388,608
  int ww = idx & 255;
  int hh = (idx >> 8) & 255;
  int cc = (idx >> 16) & 31;
  int b  = idx >> 21;
  float v = cond[idx];
  int ch = (cc << 2) | ((hh & 1) << 1) | (ww & 1);
  int y = hh >> 1, x = ww >> 1;
  int p = (b * 130 + y + 1) * 130 + 1 + x;
  u16 h = f2bf(v);
  hhi[p * 128 + ch] = h;
  hlo[p * 128 + ch] = f2bf(v - bf2f(h));
  c0[((b * 128 + y) * 128 + x) * 128 + ch] = v;
}

// ---------- weight split/reorg: to [c'][K] bf16 hi/lo -----------------------
__global__ void split_lstm_w(const float* __restrict__ w, u16* __restrict__ hi, u16* __restrict__ lo) {
  int idx = blockIdx.x * 256 + threadIdx.x;   // 512*2304
  int k = idx % 2304, c = idx / 2304;
  int tap = k >> 8, ci = k & 255;
  int gate = (c >> 4) & 3;
  int f = (c >> 7) * 32 + ((c >> 6) & 1) * 16 + (c & 15);
  float v = w[((gate * 128 + f) * 256 + ci) * 9 + tap];
  u16 h = f2bf(v); hi[idx] = h; lo[idx] = f2bf(v - bf2f(h));
}
__global__ void split_w2(const float* __restrict__ w, u16* __restrict__ hi, u16* __restrict__ lo) {
  int idx = blockIdx.x * 256 + threadIdx.x;   // 256*2304
  int k = idx % 2304, c = idx / 2304;
  int tap = k >> 8, ci = k & 255;
  float v = w[(c * 256 + ci) * 9 + tap];
  u16 h = f2bf(v); hi[idx] = h; lo[idx] = f2bf(v - bf2f(h));
}
__global__ void split_w1(const float* __restrict__ w, u16* __restrict__ hi, u16* __restrict__ lo) {
  int idx = blockIdx.x * 256 + threadIdx.x;   // 65536
  float v = w[idx];   // [c][ci] natural
  u16 h = f2bf(v); hi[idx] = h; lo[idx] = f2bf(v - bf2f(h));
}
__global__ void split_w3(const float* __restrict__ w, u16* __restrict__ hi, u16* __restrict__ lo) {
  int idx = blockIdx.x * 256 + threadIdx.x;   // 65536
  int ci = idx & 255, c = idx >> 8;
  int m = (c >> 4) & 1;
  int f = (c >> 7) * 64 + ((c >> 6) & 1) * 32 + ((c >> 5) & 1) * 16 + (c & 15);
  float v = w[(m * 128 + f) * 256 + ci];
  u16 h = f2bf(v); hi[idx] = h; lo[idx] = f2bf(v - bf2f(h));
}
__global__ void make_biases(const float* __restrict__ lb, const float* __restrict__ b1,
                            const float* __restrict__ b2, const float* __restrict__ b3,
                            float* __restrict__ pl, float* __restrict__ p1,
                            float* __restrict__ p2, float* __restrict__ p3) {
  int t = blockIdx.x * 256 + threadIdx.x;     // launch 512
  if (t < 512) {
    int gate = (t >> 4) & 3;
    int f = (t >> 7) * 32 + ((t >> 6) & 1) * 16 + (t & 15);
    pl[t] = lb[gate * 128 + f];
  }
  if (t < 256) {
    p1[t] = b1[t];
    p2[t] = b2[t];
    int m = (t >> 4) & 1;
    int f = (t >> 7) * 64 + ((t >> 6) & 1) * 32 + ((t >> 5) & 1) * 16 + (t & 15);
    p3[t] = b3[m * 128 + f];
  }
}

// ---------- MFMA conv (bf16x3 split) with prefetch + fused epilogues --------
// A: two 128-ch-slab (hi,lo) plane pairs; lo==nullptr handled via lo0/lo1=0
// (exact bf16 source -> skip lo staging and Al*Bh pass).
// skiphalf: 0 none, 1 skip ci<128 half, 2 skip ci>=128 half (zero source).
// EPI 0: LSTM update; EPI 1: lrelu -> padded/compact hi/lo; EPI 2: likelihood.
template <int TAPS, int NCOL, int EPI>
__global__ __launch_bounds__(256, 2)
void conv_mfma(const u16* __restrict__ a0hi, const u16* __restrict__ a0lo,
               const u16* __restrict__ a1hi, const u16* __restrict__ a1lo,
               int C, int RS, int PAD, int lo0, int lo1, int skiphalf,
               const u16* __restrict__ Whi, const u16* __restrict__ Wlo,
               const float* __restrict__ biasP,
               float* __restrict__ c_io,
               u16* __restrict__ ohi, u16* __restrict__ olo, int ORS, int OPAD,
               const u16* __restrict__ zsrc, float* __restrict__ lik, int g) {
  __shared__ __attribute__((aligned(16))) u16 lds[32768];  // 2 x 32KB buffers
  const int tid = threadIdx.x;
  const int lane = tid & 63, wid = tid >> 6;
  const int wm = wid >> 1, wn = wid & 1;
  const int fl = lane & 15, kq = lane >> 4;
  const int cb = blockIdx.x;
  const int Y = blockIdx.y;
  const int strip = ((Y & 7) << 6) | (Y >> 3);   // XCD-chunked swizzle
  const int b = strip >> 7, y = strip & 127;
  const int KT = TAPS * 256;
  const int NS = TAPS * (skiphalf ? 4 : 8);

  f32x4 acc[4][4] = {};
  const int apix = tid & 127, aq0 = tid >> 7;

  auto mapslab = [&](int si) -> int {
    if (!skiphalf) return si;
    int tap = si >> 2, o = si & 3;
    return tap * 8 + (skiphalf == 1 ? 4 + o : o);
  };
  auto stage = [&](int si, int bb) {
    int s = mapslab(si);
    int dy = 0, dx = 0;
    if (TAPS == 9) { int tap = s >> 3; dy = tap / 3 - 1; dx = tap % 3 - 1; }
    int ci0 = (s & 7) * 32;
    bool first = ci0 < 128;
    const u16* ahi = first ? a0hi : a1hi;
    const u16* alo = first ? a0lo : a1lo;
    bool haslo = first ? (lo0 != 0) : (lo1 != 0);
    int cib = ci0 & 127;
    int origin = (b * RS + y + PAD) * RS + PAD + dy * RS + dx;
    int gp = (origin + apix) * C + cib + aq0 * 8;
    gl16(ahi + gp,      &lds[bb + 0    + wid * 512]);
    gl16(ahi + gp + 16, &lds[bb + 2048 + wid * 512]);
    if (haslo) {
      gl16(alo + gp,      &lds[bb + 4096 + wid * 512]);
      gl16(alo + gp + 16, &lds[bb + 6144 + wid * 512]);
    }
    int wp = (cb * 128 + apix) * KT + s * 32 + aq0 * 8;
    gl16(Whi + wp,      &lds[bb + 8192  + wid * 512]);
    gl16(Whi + wp + 16, &lds[bb + 10240 + wid * 512]);
    gl16(Wlo + wp,      &lds[bb + 12288 + wid * 512]);
    gl16(Wlo + wp + 16, &lds[bb + 14336 + wid * 512]);
  };

  stage(0, 0);
  __syncthreads();
  for (int si = 0; si < NS; ++si) {
    const int bb = (si & 1) << 14;             // current buffer (u16 idx)
    if (si + 1 < NS) stage(si + 1, bb ^ 16384);  // prefetch next
    const int s = mapslab(si);
    const int ci0 = (s & 7) * 32;
    const bool haslo = (ci0 < 128) ? (lo0 != 0) : (lo1 != 0);
    const int ar = bb + kq * 1024 + (wm * 64 + fl) * 8;
    const int br = bb + 8192 + kq * 1024 + (wn * 64 + fl) * 8;
    bf16x8 Ah[4], Bh[4], Bl[4];
#pragma unroll
    for (int i = 0; i < 4; ++i) {
      Ah[i] = *(const bf16x8*)&lds[ar + i * 128];
      Bh[i] = *(const bf16x8*)&lds[br + i * 128];
      Bl[i] = *(const bf16x8*)&lds[br + 4096 + i * 128];
    }
    __builtin_amdgcn_s_setprio(1);
    if (haslo) {
      bf16x8 Al[4];
#pragma unroll
      for (int i = 0; i < 4; ++i) Al[i] = *(const bf16x8*)&lds[ar + 4096 + i * 128];
#pragma unroll
      for (int mi = 0; mi < 4; ++mi)
#pragma unroll
        for (int ni = 0; ni < 4; ++ni) {
          acc[mi][ni] = __builtin_amdgcn_mfma_f32_16x16x32_bf16(Ah[mi], Bh[ni], acc[mi][ni], 0, 0, 0);
          acc[mi][ni] = __builtin_amdgcn_mfma_f32_16x16x32_bf16(Ah[mi], Bl[ni], acc[mi][ni], 0, 0, 0);
          acc[mi][ni] = __builtin_amdgcn_mfma_f32_16x16x32_bf16(Al[mi], Bh[ni], acc[mi][ni], 0, 0, 0);
        }
    } else {
#pragma unroll
      for (int mi = 0; mi < 4; ++mi)
#pragma unroll
        for (int ni = 0; ni < 4; ++ni) {
          acc[mi][ni] = __builtin_amdgcn_mfma_f32_16x16x32_bf16(Ah[mi], Bh[ni], acc[mi][ni], 0, 0, 0);
          acc[mi][ni] = __builtin_amdgcn_mfma_f32_16x16x32_bf16(Ah[mi], Bl[ni], acc[mi][ni], 0, 0, 0);
        }
    }
    __builtin_amdgcn_s_setprio(0);
    __syncthreads();
  }

  if (EPI == 0) {
    const int f = cb * 32 + wn * 16 + fl;
    float bi[4];
#pragma unroll
    for (int ni = 0; ni < 4; ++ni) bi[ni] = biasP[cb * 128 + wn * 64 + ni * 16 + fl];
#pragma unroll
    for (int mi = 0; mi < 4; ++mi)
#pragma unroll
      for (int r = 0; r < 4; ++r) {
        int x = wm * 64 + mi * 16 + kq * 4 + r;
        int ci = ((b * 128 + y) * 128 + x) * 128 + f;
        float ig = 1.f / (1.f + expf(-(acc[mi][0][r] + bi[0])));
        float fg = 1.f / (1.f + expf(-(acc[mi][1][r] + bi[1])));
        float og = 1.f / (1.f + expf(-(acc[mi][2][r] + bi[2])));
        float gg = tanhf(acc[mi][3][r] + bi[3]);
        float cn = fg * c_io[ci] + ig * gg;
        c_io[ci] = cn;
        float hv = og * tanhf(cn);
        int hx = ((b * 130 + y + 1) * 130 + 1 + x) * 128 + f;
        u16 hb = f2bf(hv);
        ohi[hx] = hb;
        olo[hx] = f2bf(hv - bf2f(hb));
      }
  } else if (EPI == 1) {
#pragma unroll
    for (int ni = 0; ni < 4; ++ni) {
      int c = cb * 128 + wn * 64 + ni * 16 + fl;
      float bv = biasP[c];
#pragma unroll
      for (int mi = 0; mi < 4; ++mi)
#pragma unroll
        for (int r = 0; r < 4; ++r) {
          int x = wm * 64 + mi * 16 + kq * 4 + r;
          float v = acc[mi][ni][r] + bv;
          v = (v >= 0.f) ? v : 0.01f * v;
          int oi = ((b * ORS + y + OPAD) * ORS + OPAD + x) * 256 + c;
          u16 hb = f2bf(v);
          ohi[oi] = hb;
          olo[oi] = f2bf(v - bf2f(hb));
        }
    }
  } else {
#pragma unroll
    for (int j = 0; j < 2; ++j) {
      int f = cb * 64 + wn * 32 + j * 16 + fl;
      float bm = biasP[cb * 128 + wn * 64 + j * 32 + fl];
      float bs = biasP[cb * 128 + wn * 64 + j * 32 + 16 + fl];
#pragma unroll
      for (int mi = 0; mi < 4; ++mi)
#pragma unroll
        for (int r = 0; r < 4; ++r) {
          int x = wm * 64 + mi * 16 + kq * 4 + r;
          float mean = acc[mi][2 * j][r] + bm;
          float sc = fmaxf(acc[mi][2 * j + 1][r] + bs, 0.11f);
          float z = bf2f(zsrc[((b * 130 + y + 1) * 130 + 1 + x) * 128 + f]);
          float is = 0.70710678118654752f / sc;
          float up = 0.5f * (1.f + erff((z - mean + 0.5f) * is));
          float lo_ = 0.5f * (1.f + erff((z - mean - 0.5f) * is));
          lik[((b * 512 + g * 128 + f) * 128 + y) * 128 + x] = fmaxf(up - lo_, 1e-9f);
        }
    }
  }
}

// ---------- host launch ------------------------------------------------------
extern "C" void kernel_launch(void* const* d_in, const int* in_sizes, int n_in,
                              void* d_out, int out_size, void* d_ws, size_t ws_size,
                              hipStream_t stream) {
  const float* input  = (const float*)d_in[0];
  const float* cond   = (const float*)d_in[1];
  const float* lstm_w = (const float*)d_in[2];
  const float* lstm_b = (const float*)d_in[3];
  const float* w1 = (const float*)d_in[4];
  const float* b1 = (const float*)d_in[5];
  const float* w2 = (const float*)d_in[6];
  const float* b2 = (const float*)d_in[7];
  const float* w3 = (const float*)d_in[8];
  const float* b3 = (const float*)d_in[9];

  float* q   = (float*)d_out;
  float* lik = q + 33554432;

  char* ws = (char*)d_ws;
  u16* YG    = (u16*)(ws + 0);             // 4 x P128 hi planes (69,222,400 B)
  u16* HAhi  = (u16*)(ws + 69222400);
  u16* HAlo  = (u16*)(ws + 86528000);
  u16* HBhi  = (u16*)(ws + 103833600);
  u16* HBlo  = (u16*)(ws + 121139200);
  u16* T1hi  = (u16*)(ws + 138444800);     // P256
  u16* T1lo  = (u16*)(ws + 173056000);
  u16* T2hi  = (u16*)(ws + 207667200);     // compact [65536][256]
  u16* T2lo  = (u16*)(ws + 241221632);
  float* cbuf = (float*)(ws + 274776064);  // compact fp32 [65536][128]
  u16* WLhi = (u16*)(ws + 308330496);
  u16* WLlo = (u16*)(ws + 310689792);
  u16* W2hi = (u16*)(ws + 313049088);
  u16* W2lo = (u16*)(ws + 314228736);
  u16* W1hi = (u16*)(ws + 315408384);
  u16* W1lo = (u16*)(ws + 315539456);
  u16* W3hi = (u16*)(ws + 315670528);
  u16* W3lo = (u16*)(ws + 315801600);
  float* PL = (float*)(ws + 315932672);
  float* P1 = PL + 512;
  float* P2 = P1 + 256;
  float* P3 = P2 + 256;

  // zero halos of all padded activation planes (interiors rewritten below)
  hipMemsetAsync(ws, 0, 207667200, stream);

  quant_s2d_kernel<<<131072, 256, 0, stream>>>(input, q, YG);
  s2d_cond_kernel<<<32768, 256, 0, stream>>>(cond, HAhi, HAlo, cbuf);
  split_lstm_w<<<4608, 256, 0, stream>>>(lstm_w, WLhi, WLlo);
  split_w2<<<2304, 256, 0, stream>>>(w2, W2hi, W2lo);
  split_w1<<<256, 256, 0, stream>>>(w1, W1hi, W1lo);
  split_w3<<<256, 256, 0, stream>>>(w3, W3hi, W3lo);
  make_biases<<<2, 256, 0, stream>>>(lstm_b, b1, b2, b3, PL, P1, P2, P3);

  for (int g = 0; g < 4; ++g) {
    u16* hinhi  = (g & 1) ? HBhi : HAhi;
    u16* hinlo  = (g & 1) ? HBlo : HAlo;
    u16* houthi = (g & 1) ? HAhi : HBhi;
    u16* houtlo = (g & 1) ? HAlo : HBlo;
    const u16* yihi = g ? (YG + (size_t)(g - 1) * P128) : nullptr;
    const u16* zg = YG + (size_t)g * P128;

    // ConvLSTM 3x3: [yi, h] -> 512 gate cols, fused LSTM update
    conv_mfma<9, 512, 0><<<dim3(4, 512), 256, 0, stream>>>(
        yihi, nullptr, hinhi, hinlo, 128, 130, 1,
        /*lo0=*/0, /*lo1=*/1, /*skiphalf=*/g ? 0 : 1,
        WLhi, WLlo, PL, cbuf, houthi, houtlo, 0, 0, nullptr, nullptr, g);
    // w1 1x1: [h, yi] -> 256, lrelu -> t1 (padded)
    conv_mfma<1, 256, 1><<<dim3(2, 512), 256, 0, stream>>>(
        houthi, houtlo, yihi, nullptr, 128, 130, 1,
        /*lo0=*/1, /*lo1=*/0, /*skiphalf=*/g ? 0 : 2,
        W1hi, W1lo, P1, nullptr, T1hi, T1lo, 130, 1, nullptr, nullptr, g);
    // w2 3x3: t1 -> 256, lrelu -> t2 (compact)
    conv_mfma<9, 256, 1><<<dim3(2, 512), 256, 0, stream>>>(
        T1hi, T1lo, T1hi + 128, T1lo + 128, 256, 130, 1,
        1, 1, 0,
        W2hi, W2lo, P2, nullptr, T2hi, T2lo, 128, 0, nullptr, nullptr, g);
    // w3 1x1 + likelihood
    conv_mfma<1, 256, 2><<<dim3(2, 512), 256, 0, stream>>>(
        T2hi, T2lo, T2hi + 128, T2lo + 128, 256, 128, 0,
        1, 1, 0,
        W3hi, W3lo, P3, nullptr, nullptr, nullptr, 0, 0, zg, lik, g);
  }
}

// Round 5
// 3682.314 us; speedup vs baseline: 3.6095x; 1.1891x over previous
//
#include <hip/hip_runtime.h>
#include <math.h>

typedef unsigned short u16;
typedef __attribute__((ext_vector_type(8))) short bf16x8;
typedef __attribute__((ext_vector_type(4))) float f32x4;

#define P128 8652800    // elems of padded 128-ch plane: 4*130*130*128
#define P256 17305600   // elems of padded 256-ch plane

__device__ __forceinline__ u16 f2bf(float f) {
  unsigned u = __float_as_uint(f);
  unsigned r = u + 0x7fffu + ((u >> 16) & 1u);
  return (u16)(r >> 16);
}
__device__ __forceinline__ float bf2f(u16 h) {
  return __uint_as_float(((unsigned)h) << 16);
}
__device__ __forceinline__ void gl16(const u16* g, const u16* l) {
  __builtin_amdgcn_global_load_lds(
      (const __attribute__((address_space(1))) void*)g,
      (__attribute__((address_space(3))) void*)l, 16, 0, 0);
}

// ---------- quantize + s2d into padded bf16 group planes --------------------
__global__ void quant_s2d_kernel(const float* __restrict__ inp,
                                 float* __restrict__ q,
                                 u16* __restrict__ yghi) {
  int idx = blockIdx.x * 256 + threadIdx.x;   // 33,554,432
  int ww = idx & 255;
  int hh = (idx >> 8) & 255;
  int cc = (idx >> 16) & 127;
  int b  = idx >> 23;
  float v = rintf(inp[idx]);
  q[idx] = v;
  int g = cc >> 5;
  int f = ((cc & 31) << 2) | ((hh & 1) << 1) | (ww & 1);
  int y = hh >> 1, x = ww >> 1;
  int p = (b * 130 + y + 1) * 130 + 1 + x;
  yghi[g * P128 + p * 128 + f] = f2bf(v);   // small integer -> exact
}

// ---------- s2d of condition -> h0 hi/lo (padded) + c0 (compact fp32) -------
__global__ void s2d_cond_kernel(const float* __restrict__ cond,
                                u16* __restrict__ hhi, u16* __restrict__ hlo,
                                float* __restrict__ c0) {
  int idx = blockIdx.x * 256 + threadIdx.x;   // 8,388,608
  int ww = idx & 255;
  int hh = (idx >> 8) & 255;
  int cc = (idx >> 16) & 31;
  int b  = idx >> 21;
  float v = cond[idx];
  int ch = (cc << 2) | ((hh & 1) << 1) | (ww & 1);
  int y = hh >> 1, x = ww >> 1;
  int p = (b * 130 + y + 1) * 130 + 1 + x;
  u16 h = f2bf(v);
  hhi[p * 128 + ch] = h;
  hlo[p * 128 + ch] = f2bf(v - bf2f(h));
  c0[((b * 128 + y) * 128 + x) * 128 + ch] = v;
}

// ---------- weight pack: per (cb*2+wn, slab) wave-fragment layout -----------
// out[(cbwn*NSLAB + slab)][plane(hi/lo)][ni][lane][8]  (4096 u16 per slab blk)
// lane fragment: col = cbwn*64 + ni*16 + (lane&15); k = slab*32 + (lane>>4)*8 + j
// PERM 0: LSTM gate perm; 1: identity; 2: w3 mean/scale perm
template <int TAPS, int PERM>
__global__ void build_wpack(const float* __restrict__ w, u16* __restrict__ o) {
  int idx = blockIdx.x * 256 + threadIdx.x;
  int jj = idx & 7, lane = (idx >> 3) & 63, ni = (idx >> 9) & 3, plane = (idx >> 11) & 1;
  int rest = idx >> 12;
  const int NSLAB = TAPS * 8;
  int slab = rest % NSLAB, cbwn = rest / NSLAB;
  int c = cbwn * 64 + ni * 16 + (lane & 15);
  int k = slab * 32 + ((lane >> 4) << 3) + jj;
  int tap = (TAPS == 9) ? (k >> 8) : 0;
  int ci = (TAPS == 9) ? (k & 255) : k;
  int oc;
  if (PERM == 0)      oc = ((c >> 4) & 3) * 128 + (c >> 7) * 32 + ((c >> 6) & 1) * 16 + (c & 15);
  else if (PERM == 2) oc = ((c >> 4) & 1) * 128 + (c >> 7) * 64 + ((c >> 6) & 1) * 32 + ((c >> 5) & 1) * 16 + (c & 15);
  else                oc = c;
  float v = w[((size_t)(oc * 256 + ci)) * TAPS + tap];
  u16 h = f2bf(v);
  o[idx] = plane ? f2bf(v - bf2f(h)) : h;
}

__global__ void make_biases(const float* __restrict__ lb, const float* __restrict__ b1,
                            const float* __restrict__ b2, const float* __restrict__ b3,
                            float* __restrict__ pl, float* __restrict__ p1,
                            float* __restrict__ p2, float* __restrict__ p3) {
  int t = blockIdx.x * 256 + threadIdx.x;     // launch 512
  if (t < 512) {
    int gate = (t >> 4) & 3;
    int f = (t >> 7) * 32 + ((t >> 6) & 1) * 16 + (t & 15);
    pl[t] = lb[gate * 128 + f];
  }
  if (t < 256) {
    p1[t] = b1[t];
    p2[t] = b2[t];
    int m = (t >> 4) & 1;
    int f = (t >> 7) * 64 + ((t >> 6) & 1) * 32 + ((t >> 5) & 1) * 16 + (t & 15);
    p3[t] = b3[m * 128 + f];
  }
}

// ---------- MFMA conv: A via 3-deep LDS pipeline, W via reg double-buffer ---
// vmcnt protocol: windows between memory-clobber asms are hermetic (loads and
// global_load_lds cannot cross asm with "memory"). In-loop wait uses the
// WORST-CASE within-window reorder count: after A(sk)'s last op at most
// window(sk)=[A(sk+1)x4, W(sk+1)x8]=12 ops follow -> vmcnt(12) guarantees
// A(sk) complete. Last iteration: following window empty -> vmcnt(0).
// Prologue issue order pinned with sched_barrier(0).
template <int TAPS, int NCOL, int EPI>
__global__ __launch_bounds__(256, 2)
void conv_mfma(const u16* __restrict__ a0hi, const u16* __restrict__ a0lo,
               const u16* __restrict__ a1hi, const u16* __restrict__ a1lo,
               int C, int RS, int PAD, int lo0, int lo1, int skiphalf,
               const u16* __restrict__ Wpk, const float* __restrict__ biasP,
               float* __restrict__ c_io,
               u16* __restrict__ ohi, u16* __restrict__ olo, int ORS, int OPAD,
               const u16* __restrict__ zsrc, float* __restrict__ lik, int g) {
  constexpr int NSLAB = TAPS * 8;
  constexpr int NCB = NCOL / 128;
  __shared__ __attribute__((aligned(16))) u16 lds[24576];  // 3 x 16KB A buffers
  const int tid = threadIdx.x;
  const int lane = tid & 63, wid = tid >> 6;
  const int wm = wid >> 1, wn = wid & 1;
  const int fl = lane & 15, kq = lane >> 4;

  // XCD swizzle: windows of 512 blocks; each XCD gets contiguous y-strips x all cb
  int n = blockIdx.y * NCB + blockIdx.x;
  int w_ = n >> 9, r_ = n & 511;
  int xj = r_ & 7, tt = r_ >> 3;
  const int cb = tt & (NCB - 1);
  const int YL = 64 / NCB;
  int ystrip = w_ * (8 * YL) + xj * YL + (tt / NCB);
  const int b = ystrip >> 7, y = ystrip & 127;

  const int NS = skiphalf ? NSLAB / 2 : NSLAB;
  f32x4 acc[4][4] = {};

  const int pix = tid & 127, kqa = tid >> 7;
  const u16* wbase = Wpk + (size_t)(cb * 2 + wn) * NSLAB * 4096;

  auto mapslab = [&](int si) -> int {
    if (!skiphalf) return si;
    int tap = si >> 2, o = si & 3;
    return tap * 8 + (skiphalf == 1 ? 4 + o : o);
  };
  auto issueA = [&](int si, int buf) {   // 4 gl16 per wave
    int s = mapslab(si);
    int dy = 0, dx = 0;
    if (TAPS == 9) { int tap = s >> 3; dy = tap / 3 - 1; dx = tap % 3 - 1; }
    int ci0 = (s & 7) * 32;
    bool first = ci0 < 128;
    const u16* ahi = first ? a0hi : a1hi;
    const u16* alo = first ? (lo0 ? a0lo : a0hi) : (lo1 ? a1lo : a1hi);
    int cib = ci0 & 127;
    size_t gp = (size_t)((b * RS + y + PAD) * RS + PAD + dy * RS + dx + pix) * C + cib;
    const u16* lb = &lds[buf * 8192 + wid * 512];
    gl16(ahi + gp + kqa * 8,       lb);
    gl16(ahi + gp + (kqa + 2) * 8, lb + 2048);
    gl16(alo + gp + kqa * 8,       lb + 4096);
    gl16(alo + gp + (kqa + 2) * 8, lb + 6144);
  };
  auto issueW = [&](int si, bf16x8* W) {  // 8 coalesced dwordx4 per wave
    int s = mapslab(si);
    const bf16x8* wp = (const bf16x8*)(wbase + (size_t)s * 4096);
#pragma unroll
    for (int i = 0; i < 8; ++i) W[i] = wp[i * 64 + lane];
  };
  auto compute = [&](int si, const bf16x8* W, int buf) {
    int s = mapslab(si);
    bool haslo = ((s & 7) * 32 < 128) ? (lo0 != 0) : (lo1 != 0);
    const u16* ab = &lds[buf * 8192 + kq * 1024 + (wm * 64 + fl) * 8];
    bf16x8 Ah[4];
#pragma unroll
    for (int i = 0; i < 4; ++i) Ah[i] = *(const bf16x8*)(ab + i * 128);
    __builtin_amdgcn_s_setprio(1);
#pragma unroll
    for (int mi = 0; mi < 4; ++mi)
#pragma unroll
      for (int ni = 0; ni < 4; ++ni) {
        acc[mi][ni] = __builtin_amdgcn_mfma_f32_16x16x32_bf16(Ah[mi], W[ni], acc[mi][ni], 0, 0, 0);
        acc[mi][ni] = __builtin_amdgcn_mfma_f32_16x16x32_bf16(Ah[mi], W[4 + ni], acc[mi][ni], 0, 0, 0);
      }
    if (haslo) {
      bf16x8 Al[4];
#pragma unroll
      for (int i = 0; i < 4; ++i) Al[i] = *(const bf16x8*)(ab + 4096 + i * 128);
#pragma unroll
      for (int mi = 0; mi < 4; ++mi)
#pragma unroll
        for (int ni = 0; ni < 4; ++ni)
          acc[mi][ni] = __builtin_amdgcn_mfma_f32_16x16x32_bf16(Al[mi], W[ni], acc[mi][ni], 0, 0, 0);
    }
    __builtin_amdgcn_s_setprio(0);
  };

  bf16x8 WA[8], WB[8];
  // Prologue — order PINNED so vmcnt accounting holds: A(0), W(0), A(1).
  issueA(0, 0);
  __builtin_amdgcn_sched_barrier(0);
  issueW(0, WA);
  __builtin_amdgcn_sched_barrier(0);
  issueA(1, 1);
  __builtin_amdgcn_sched_barrier(0);

#define BODY(SI, WCUR, WNXT, ABUF)                                          \
  {                                                                         \
    int si_ = (SI);                                                         \
    if (si_ + 1 < NS) issueW(si_ + 1, WNXT);                                \
    /* conservative FIFO count: see header comment */                       \
    if (si_ + 1 < NS) asm volatile("s_waitcnt vmcnt(12)" ::: "memory");     \
    else              asm volatile("s_waitcnt vmcnt(0)" ::: "memory");      \
    __builtin_amdgcn_s_barrier();                                           \
    __builtin_amdgcn_sched_barrier(0);                                      \
    int tb_ = (ABUF) + 2; if (tb_ >= 3) tb_ -= 3;                           \
    if (si_ + 2 < NS) issueA(si_ + 2, tb_);                                 \
    compute(si_, WCUR, (ABUF));                                             \
  }

  int bc = 0;
  for (int si = 0; si < NS; si += 2) {   // NS is always even
    BODY(si, WA, WB, bc);
    int b2 = bc + 1; if (b2 >= 3) b2 -= 3;
    BODY(si + 1, WB, WA, b2);
    bc += 2; if (bc >= 3) bc -= 3;
  }
#undef BODY

  if (EPI == 0) {
    const int f = cb * 32 + wn * 16 + fl;
    float bi[4];
#pragma unroll
    for (int ni = 0; ni < 4; ++ni) bi[ni] = biasP[cb * 128 + wn * 64 + ni * 16 + fl];
#pragma unroll
    for (int mi = 0; mi < 4; ++mi)
#pragma unroll
      for (int r = 0; r < 4; ++r) {
        int x = wm * 64 + mi * 16 + kq * 4 + r;
        int ci = ((b * 128 + y) * 128 + x) * 128 + f;
        float ig = 1.f / (1.f + expf(-(acc[mi][0][r] + bi[0])));
        float fg = 1.f / (1.f + expf(-(acc[mi][1][r] + bi[1])));
        float og = 1.f / (1.f + expf(-(acc[mi][2][r] + bi[2])));
        float gg = tanhf(acc[mi][3][r] + bi[3]);
        float cn = fg * c_io[ci] + ig * gg;
        c_io[ci] = cn;
        float hv = og * tanhf(cn);
        int hx = ((b * 130 + y + 1) * 130 + 1 + x) * 128 + f;
        u16 hb = f2bf(hv);
        ohi[hx] = hb;
        olo[hx] = f2bf(hv - bf2f(hb));
      }
  } else if (EPI == 1) {
#pragma unroll
    for (int ni = 0; ni < 4; ++ni) {
      int c = cb * 128 + wn * 64 + ni * 16 + fl;
      float bv = biasP[c];
#pragma unroll
      for (int mi = 0; mi < 4; ++mi)
#pragma unroll
        for (int r = 0; r < 4; ++r) {
          int x = wm * 64 + mi * 16 + kq * 4 + r;
          float v = acc[mi][ni][r] + bv;
          v = (v >= 0.f) ? v : 0.01f * v;
          int oi = ((b * ORS + y + OPAD) * ORS + OPAD + x) * 256 + c;
          u16 hb = f2bf(v);
          ohi[oi] = hb;
          olo[oi] = f2bf(v - bf2f(hb));
        }
    }
  } else {
#pragma unroll
    for (int j = 0; j < 2; ++j) {
      int f = cb * 64 + wn * 32 + j * 16 + fl;
      float bm = biasP[cb * 128 + wn * 64 + j * 32 + fl];
      float bs = biasP[cb * 128 + wn * 64 + j * 32 + 16 + fl];
#pragma unroll
      for (int mi = 0; mi < 4; ++mi)
#pragma unroll
        for (int r = 0; r < 4; ++r) {
          int x = wm * 64 + mi * 16 + kq * 4 + r;
          float mean = acc[mi][2 * j][r] + bm;
          float sc = fmaxf(acc[mi][2 * j + 1][r] + bs, 0.11f);
          float z = bf2f(zsrc[((b * 130 + y + 1) * 130 + 1 + x) * 128 + f]);
          float is = 0.70710678118654752f / sc;
          float up = 0.5f * (1.f + erff((z - mean + 0.5f) * is));
          float lo_ = 0.5f * (1.f + erff((z - mean - 0.5f) * is));
          lik[((b * 512 + g * 128 + f) * 128 + y) * 128 + x] = fmaxf(up - lo_, 1e-9f);
        }
    }
  }
}

// ---------- host launch ------------------------------------------------------
extern "C" void kernel_launch(void* const* d_in, const int* in_sizes, int n_in,
                              void* d_out, int out_size, void* d_ws, size_t ws_size,
                              hipStream_t stream) {
  const float* input  = (const float*)d_in[0];
  const float* cond   = (const float*)d_in[1];
  const float* lstm_w = (const float*)d_in[2];
  const float* lstm_b = (const float*)d_in[3];
  const float* w1 = (const float*)d_in[4];
  const float* b1 = (const float*)d_in[5];
  const float* w2 = (const float*)d_in[6];
  const float* b2 = (const float*)d_in[7];
  const float* w3 = (const float*)d_in[8];
  const float* b3 = (const float*)d_in[9];

  float* q   = (float*)d_out;
  float* lik = q + 33554432;

  char* ws = (char*)d_ws;
  u16* YG    = (u16*)(ws + 0);             // 4 x P128 hi planes
  u16* HAhi  = (u16*)(ws + 69222400);
  u16* HAlo  = (u16*)(ws + 86528000);
  u16* HBhi  = (u16*)(ws + 103833600);
  u16* HBlo  = (u16*)(ws + 121139200);
  u16* T1hi  = (u16*)(ws + 138444800);     // P256 padded
  u16* T1lo  = (u16*)(ws + 173056000);
  u16* T2hi  = (u16*)(ws + 207667200);     // compact [65536][256]
  u16* T2lo  = (u16*)(ws + 241221632);
  float* cbuf = (float*)(ws + 274776064);  // compact fp32 [65536][128]
  u16* WLpk = (u16*)(ws + 308330496);      // 8 x 72 x 4096 u16
  u16* W2pk = (u16*)(ws + 313049088);      // 4 x 72 x 4096
  u16* W1pk = (u16*)(ws + 315408384);      // 4 x 8 x 4096
  u16* W3pk = (u16*)(ws + 315670528);      // 4 x 8 x 4096
  float* PL = (float*)(ws + 315932672);
  float* P1 = PL + 512;
  float* P2 = P1 + 256;
  float* P3 = P2 + 256;

  // zero halos of all padded activation planes (interiors rewritten below)
  hipMemsetAsync(ws, 0, 207667200, stream);

  quant_s2d_kernel<<<131072, 256, 0, stream>>>(input, q, YG);
  s2d_cond_kernel<<<32768, 256, 0, stream>>>(cond, HAhi, HAlo, cbuf);
  build_wpack<9, 0><<<9216, 256, 0, stream>>>(lstm_w, WLpk);
  build_wpack<9, 1><<<4608, 256, 0, stream>>>(w2, W2pk);
  build_wpack<1, 1><<<512, 256, 0, stream>>>(w1, W1pk);
  build_wpack<1, 2><<<512, 256, 0, stream>>>(w3, W3pk);
  make_biases<<<2, 256, 0, stream>>>(lstm_b, b1, b2, b3, PL, P1, P2, P3);

  for (int g = 0; g < 4; ++g) {
    u16* hinhi  = (g & 1) ? HBhi : HAhi;
    u16* hinlo  = (g & 1) ? HBlo : HAlo;
    u16* houthi = (g & 1) ? HAhi : HBhi;
    u16* houtlo = (g & 1) ? HAlo : HBlo;
    const u16* yihi = g ? (YG + (size_t)(g - 1) * P128) : hinhi;  // g=0: dead (skipped)
    const u16* zg = YG + (size_t)g * P128;

    // ConvLSTM 3x3: [yi, h] -> 512 gate cols, fused LSTM update
    conv_mfma<9, 512, 0><<<dim3(4, 512), 256, 0, stream>>>(
        yihi, yihi, hinhi, hinlo, 128, 130, 1,
        /*lo0=*/0, /*lo1=*/1, /*skiphalf=*/g ? 0 : 1,
        WLpk, PL, cbuf, houthi, houtlo, 0, 0, nullptr, nullptr, g);
    // w1 1x1: [h, yi] -> 256, lrelu -> t1 (padded)
    conv_mfma<1, 256, 1><<<dim3(2, 512), 256, 0, stream>>>(
        houthi, houtlo, yihi, yihi, 128, 130, 1,
        /*lo0=*/1, /*lo1=*/0, /*skiphalf=*/g ? 0 : 2,
        W1pk, P1, nullptr, T1hi, T1lo, 130, 1, nullptr, nullptr, g);
    // w2 3x3: t1 -> 256, lrelu -> t2 (compact)
    conv_mfma<9, 256, 1><<<dim3(2, 512), 256, 0, stream>>>(
        T1hi, T1lo, T1hi + 128, T1lo + 128, 256, 130, 1,
        1, 1, 0,
        W2pk, P2, nullptr, T2hi, T2lo, 128, 0, nullptr, nullptr, g);
    // w3 1x1 + likelihood
    conv_mfma<1, 256, 2><<<dim3(2, 512), 256, 0, stream>>>(
        T2hi, T2lo, T2hi + 128, T2lo + 128, 256, 128, 0,
        1, 1, 0,
        W3pk, P3, nullptr, nullptr, nullptr, 0, 0, zg, lik, g);
  }
}

// Round 6
// 2537.899 us; speedup vs baseline: 5.2372x; 1.4509x over previous
//
#include <hip/hip_runtime.h>
#include <math.h>

typedef unsigned short u16;
typedef __attribute__((ext_vector_type(8))) short bf16x8;
typedef __attribute__((ext_vector_type(4))) float f32x4;

#define P128 8652800    // elems of padded 128-ch plane: 4*130*130*128
#define P256 17305600   // elems of padded 256-ch plane

__device__ __forceinline__ u16 f2bf(float f) {
  unsigned u = __float_as_uint(f);
  unsigned r = u + 0x7fffu + ((u >> 16) & 1u);
  return (u16)(r >> 16);
}
__device__ __forceinline__ float bf2f(u16 h) {
  return __uint_as_float(((unsigned)h) << 16);
}
__device__ __forceinline__ void gl16(const u16* g, const u16* l) {
  __builtin_amdgcn_global_load_lds(
      (const __attribute__((address_space(1))) void*)g,
      (__attribute__((address_space(3))) void*)l, 16, 0, 0);
}

// ---------- quantize + s2d into padded bf16 group planes --------------------
__global__ void quant_s2d_kernel(const float* __restrict__ inp,
                                 float* __restrict__ q,
                                 u16* __restrict__ yghi) {
  int idx = blockIdx.x * 256 + threadIdx.x;   // 33,554,432
  int ww = idx & 255;
  int hh = (idx >> 8) & 255;
  int cc = (idx >> 16) & 127;
  int b  = idx >> 23;
  float v = rintf(inp[idx]);
  q[idx] = v;
  int g = cc >> 5;
  int f = ((cc & 31) << 2) | ((hh & 1) << 1) | (ww & 1);
  int y = hh >> 1, x = ww >> 1;
  int p = (b * 130 + y + 1) * 130 + 1 + x;
  yghi[g * P128 + p * 128 + f] = f2bf(v);   // small integer -> exact
}

// ---------- s2d of condition -> h0 hi/lo (padded) + c0 (compact fp32) -------
__global__ void s2d_cond_kernel(const float* __restrict__ cond,
                                u16* __restrict__ hhi, u16* __restrict__ hlo,
                                float* __restrict__ c0) {
  int idx = blockIdx.x * 256 + threadIdx.x;   // 8,388,608
  int ww = idx & 255;
  int hh = (idx >> 8) & 255;
  int cc = (idx >> 16) & 31;
  int b  = idx >> 21;
  float v = cond[idx];
  int ch = (cc << 2) | ((hh & 1) << 1) | (ww & 1);
  int y = hh >> 1, x = ww >> 1;
  int p = (b * 130 + y + 1) * 130 + 1 + x;
  u16 h = f2bf(v);
  hhi[p * 128 + ch] = h;
  hlo[p * 128 + ch] = f2bf(v - bf2f(h));
  c0[((b * 128 + y) * 128 + x) * 128 + ch] = v;
}

// ---------- weight pack: per (cb*2+wn, slab) wave-fragment layout -----------
// out[(cbwn*NSLAB + slab)][plane(hi/lo)][ni][lane][8]  (4096 u16 per slab blk)
// lane fragment: col = cbwn*64 + ni*16 + (lane&15); k = slab*32 + (lane>>4)*8 + j
// PERM 0: LSTM gate perm; 1: identity; 2: w3 mean/scale perm
template <int TAPS, int PERM>
__global__ void build_wpack(const float* __restrict__ w, u16* __restrict__ o) {
  int idx = blockIdx.x * 256 + threadIdx.x;
  int jj = idx & 7, lane = (idx >> 3) & 63, ni = (idx >> 9) & 3, plane = (idx >> 11) & 1;
  int rest = idx >> 12;
  const int NSLAB = TAPS * 8;
  int slab = rest % NSLAB, cbwn = rest / NSLAB;
  int c = cbwn * 64 + ni * 16 + (lane & 15);
  int k = slab * 32 + ((lane >> 4) << 3) + jj;
  int tap = (TAPS == 9) ? (k >> 8) : 0;
  int ci = (TAPS == 9) ? (k & 255) : k;
  int oc;
  if (PERM == 0)      oc = ((c >> 4) & 3) * 128 + (c >> 7) * 32 + ((c >> 6) & 1) * 16 + (c & 15);
  else if (PERM == 2) oc = ((c >> 4) & 1) * 128 + (c >> 7) * 64 + ((c >> 6) & 1) * 32 + ((c >> 5) & 1) * 16 + (c & 15);
  else                oc = c;
  float v = w[((size_t)(oc * 256 + ci)) * TAPS + tap];
  u16 h = f2bf(v);
  o[idx] = plane ? f2bf(v - bf2f(h)) : h;
}

__global__ void make_biases(const float* __restrict__ lb, const float* __restrict__ b1,
                            const float* __restrict__ b2, const float* __restrict__ b3,
                            float* __restrict__ pl, float* __restrict__ p1,
                            float* __restrict__ p2, float* __restrict__ p3) {
  int t = blockIdx.x * 256 + threadIdx.x;     // launch 512
  if (t < 512) {
    int gate = (t >> 4) & 3;
    int f = (t >> 7) * 32 + ((t >> 6) & 1) * 16 + (t & 15);
    pl[t] = lb[gate * 128 + f];
  }
  if (t < 256) {
    p1[t] = b1[t];
    p2[t] = b2[t];
    int m = (t >> 4) & 1;
    int f = (t >> 7) * 64 + ((t >> 6) & 1) * 32 + ((t >> 5) & 1) * 16 + (t & 15);
    p3[t] = b3[m * 128 + f];
  }
}

// ---------- MFMA conv: BARRIER-FREE per-wave pipeline -----------------------
// Each wave stages its OWN 64-pixel A-region into a private LDS segment via
// global_load_lds (counts on the issuing wave's vmcnt -> per-wave counted
// vmcnt protocol, no s_barrier anywhere). Prefetch distance 1, 2 buffers.
// Windows between "memory"-clobber asms are hermetic; each window issues
// exactly WINOPS vmem ops, so s_waitcnt vmcnt(WINOPS) guarantees the previous
// window's A-DMA + W-loads completed. lgkmcnt(0) before re-staging a buffer
// guarantees prior ds_reads of that buffer finished.
// LOANY: stage lo plane (LSTM). WLO: do Ah*Blo pass + load W-lo (LSTM).
// EPI 0: LSTM update; EPI 1: lrelu -> hi only; EPI 2: likelihood.
template <int TAPS, int NCOL, int EPI, int LOANY, int WLO>
__global__ __launch_bounds__(256, 2)
void conv_mfma(const u16* __restrict__ a0hi, const u16* __restrict__ a0lo,
               const u16* __restrict__ a1hi, const u16* __restrict__ a1lo,
               int C, int RS, int PAD, int lo0, int lo1, int skiphalf,
               const u16* __restrict__ Wpk, const float* __restrict__ biasP,
               float* __restrict__ c_io,
               u16* __restrict__ ohi, u16* __restrict__ olo, int ORS, int OPAD,
               const u16* __restrict__ zsrc, float* __restrict__ lik, int g) {
  constexpr int NSLAB = TAPS * 8;
  constexpr int NCB = NCOL / 128;
  constexpr int WV = LOANY ? 4096 : 2048;     // u16 per wave-buffer segment
  constexpr int NWF = WLO ? 8 : 4;            // W fragments per slab
  __shared__ __attribute__((aligned(16))) u16 lds[8 * WV];  // 2 bufs x 4 waves
  const int tid = threadIdx.x;
  const int lane = tid & 63, wid = tid >> 6;
  const int wm = wid >> 1, wn = wid & 1;
  const int fl = lane & 15, kq = lane >> 4;

  // XCD swizzle: windows of 512 blocks; each XCD gets contiguous y-strips x all cb
  int n = blockIdx.y * NCB + blockIdx.x;
  int w_ = n >> 9, r_ = n & 511;
  int xj = r_ & 7, tt = r_ >> 3;
  const int cb = tt & (NCB - 1);
  const int YL = 64 / NCB;
  int ystrip = w_ * (8 * YL) + xj * YL + (tt / NCB);
  const int b = ystrip >> 7, y = ystrip & 127;

  const int NS = skiphalf ? NSLAB / 2 : NSLAB;
  f32x4 acc[4][4] = {};

  const u16* wbase = Wpk + (size_t)(cb * 2 + wn) * NSLAB * 4096;

  auto mapslab = [&](int si) -> int {
    if (!skiphalf) return si;
    int tap = si >> 2, o = si & 3;
    return tap * 8 + (skiphalf == 1 ? 4 + o : o);
  };
  // Per-wave A staging: 64 pixels x 32 k (hi [+ lo]) into own segment.
  auto issueA = [&](int si, int buf) {   // 4 (or 8) gl16 per wave
    int s = mapslab(si);
    int dy = 0, dx = 0;
    if (TAPS == 9) { int tap = s >> 3; dy = tap / 3 - 1; dx = tap % 3 - 1; }
    int ci0 = (s & 7) * 32;
    bool first = ci0 < 128;
    const u16* ahi = first ? a0hi : a1hi;
    int cib = ci0 & 127;
    int origin = (b * RS + y + PAD) * RS + PAD + dy * RS + dx;
    size_t rowb = (size_t)(origin + wm * 64 + (lane >> 2)) * C + cib + (lane & 3) * 8;
    const u16* lb = &lds[buf * 4 * WV + wid * WV];
#pragma unroll
    for (int c = 0; c < 4; ++c)
      gl16(ahi + rowb + (size_t)(c * 16) * C, lb + c * 512);
    if (LOANY) {
      const u16* alo = first ? (lo0 ? a0lo : a0hi) : (lo1 ? a1lo : a1hi);
#pragma unroll
      for (int c = 0; c < 4; ++c)
        gl16(alo + rowb + (size_t)(c * 16) * C, lb + 2048 + c * 512);
    }
  };
  auto issueW = [&](int si, bf16x8* W) {  // NWF coalesced dwordx4 per wave
    int s = mapslab(si);
    const bf16x8* wp = (const bf16x8*)(wbase + (size_t)s * 4096);
#pragma unroll
    for (int i = 0; i < NWF; ++i) W[i] = wp[i * 64 + lane];
  };
  auto compute = [&](int si, const bf16x8* W, int buf) {
    int s = mapslab(si);
    bool haslo = LOANY && ((((s & 7) * 32) < 128) ? (lo0 != 0) : (lo1 != 0));
    const u16* ab = &lds[buf * 4 * WV + wid * WV + fl * 32 + kq * 8];
    bf16x8 Ah[4];
#pragma unroll
    for (int i = 0; i < 4; ++i) Ah[i] = *(const bf16x8*)(ab + i * 512);
    __builtin_amdgcn_s_setprio(1);
#pragma unroll
    for (int mi = 0; mi < 4; ++mi)
#pragma unroll
      for (int ni = 0; ni < 4; ++ni)
        acc[mi][ni] = __builtin_amdgcn_mfma_f32_16x16x32_bf16(Ah[mi], W[ni], acc[mi][ni], 0, 0, 0);
    if (WLO) {
#pragma unroll
      for (int mi = 0; mi < 4; ++mi)
#pragma unroll
        for (int ni = 0; ni < 4; ++ni)
          acc[mi][ni] = __builtin_amdgcn_mfma_f32_16x16x32_bf16(Ah[mi], W[4 + ni], acc[mi][ni], 0, 0, 0);
    }
    if (haslo) {
      bf16x8 Al[4];
#pragma unroll
      for (int i = 0; i < 4; ++i) Al[i] = *(const bf16x8*)(ab + 2048 + i * 512);
#pragma unroll
      for (int mi = 0; mi < 4; ++mi)
#pragma unroll
        for (int ni = 0; ni < 4; ++ni)
          acc[mi][ni] = __builtin_amdgcn_mfma_f32_16x16x32_bf16(Al[mi], W[ni], acc[mi][ni], 0, 0, 0);
    }
    __builtin_amdgcn_s_setprio(0);
  };

#define LGKM0() asm volatile("s_waitcnt lgkmcnt(0)" ::: "memory")
#define WAITWIN()                                                      \
  do {                                                                 \
    if constexpr (LOANY && WLO) asm volatile("s_waitcnt vmcnt(16)" ::: "memory"); \
    else                        asm volatile("s_waitcnt vmcnt(8)" ::: "memory");  \
  } while (0)

  bf16x8 WA[8], WB[8];
  issueA(0, 0);
  issueW(0, WA);
  for (int si = 0; si < NS; si += 2) {   // NS always even
    LGKM0();                             // buf1 ds_reads (prev iter) done
    issueA(si + 1, 1);
    issueW(si + 1, WB);
    WAITWIN();                           // A(si), W(si) landed
    compute(si, WA, 0);
    if (si + 2 < NS) {
      LGKM0();                           // buf0 ds_reads done
      issueA(si + 2, 0);
      issueW(si + 2, WA);
      WAITWIN();                         // A(si+1), W(si+1) landed
    } else {
      asm volatile("s_waitcnt vmcnt(0)" ::: "memory");
    }
    compute(si + 1, WB, 1);
  }
#undef LGKM0
#undef WAITWIN

  if (EPI == 0) {
    const int f = cb * 32 + wn * 16 + fl;
    float bi[4];
#pragma unroll
    for (int ni = 0; ni < 4; ++ni) bi[ni] = biasP[cb * 128 + wn * 64 + ni * 16 + fl];
#pragma unroll
    for (int mi = 0; mi < 4; ++mi)
#pragma unroll
      for (int r = 0; r < 4; ++r) {
        int x = wm * 64 + mi * 16 + kq * 4 + r;
        int ci = ((b * 128 + y) * 128 + x) * 128 + f;
        float ig = 1.f / (1.f + expf(-(acc[mi][0][r] + bi[0])));
        float fg = 1.f / (1.f + expf(-(acc[mi][1][r] + bi[1])));
        float og = 1.f / (1.f + expf(-(acc[mi][2][r] + bi[2])));
        float gg = tanhf(acc[mi][3][r] + bi[3]);
        float cn = fg * c_io[ci] + ig * gg;
        c_io[ci] = cn;
        float hv = og * tanhf(cn);
        int hx = ((b * 130 + y + 1) * 130 + 1 + x) * 128 + f;
        u16 hb = f2bf(hv);
        ohi[hx] = hb;
        olo[hx] = f2bf(hv - bf2f(hb));
      }
  } else if (EPI == 1) {
#pragma unroll
    for (int ni = 0; ni < 4; ++ni) {
      int c = cb * 128 + wn * 64 + ni * 16 + fl;
      float bv = biasP[c];
#pragma unroll
      for (int mi = 0; mi < 4; ++mi)
#pragma unroll
        for (int r = 0; r < 4; ++r) {
          int x = wm * 64 + mi * 16 + kq * 4 + r;
          float v = acc[mi][ni][r] + bv;
          v = (v >= 0.f) ? v : 0.01f * v;
          int oi = ((b * ORS + y + OPAD) * ORS + OPAD + x) * 256 + c;
          ohi[oi] = f2bf(v);
        }
    }
  } else {
#pragma unroll
    for (int j = 0; j < 2; ++j) {
      int f = cb * 64 + wn * 32 + j * 16 + fl;
      float bm = biasP[cb * 128 + wn * 64 + j * 32 + fl];
      float bs = biasP[cb * 128 + wn * 64 + j * 32 + 16 + fl];
#pragma unroll
      for (int mi = 0; mi < 4; ++mi)
#pragma unroll
        for (int r = 0; r < 4; ++r) {
          int x = wm * 64 + mi * 16 + kq * 4 + r;
          float mean = acc[mi][2 * j][r] + bm;
          float sc = fmaxf(acc[mi][2 * j + 1][r] + bs, 0.11f);
          float z = bf2f(zsrc[((b * 130 + y + 1) * 130 + 1 + x) * 128 + f]);
          float is = 0.70710678118654752f / sc;
          float up = 0.5f * (1.f + erff((z - mean + 0.5f) * is));
          float lo_ = 0.5f * (1.f + erff((z - mean - 0.5f) * is));
          lik[((b * 512 + g * 128 + f) * 128 + y) * 128 + x] = fmaxf(up - lo_, 1e-9f);
        }
    }
  }
}

// ---------- host launch ------------------------------------------------------
extern "C" void kernel_launch(void* const* d_in, const int* in_sizes, int n_in,
                              void* d_out, int out_size, void* d_ws, size_t ws_size,
                              hipStream_t stream) {
  const float* input  = (const float*)d_in[0];
  const float* cond   = (const float*)d_in[1];
  const float* lstm_w = (const float*)d_in[2];
  const float* lstm_b = (const float*)d_in[3];
  const float* w1 = (const float*)d_in[4];
  const float* b1 = (const float*)d_in[5];
  const float* w2 = (const float*)d_in[6];
  const float* b2 = (const float*)d_in[7];
  const float* w3 = (const float*)d_in[8];
  const float* b3 = (const float*)d_in[9];

  float* q   = (float*)d_out;
  float* lik = q + 33554432;

  char* ws = (char*)d_ws;
  u16* YG    = (u16*)(ws + 0);             // 4 x P128 hi planes
  u16* HAhi  = (u16*)(ws + 69222400);
  u16* HAlo  = (u16*)(ws + 86528000);
  u16* HBhi  = (u16*)(ws + 103833600);
  u16* HBlo  = (u16*)(ws + 121139200);
  u16* T1hi  = (u16*)(ws + 138444800);     // P256 padded (hi only used)
  u16* T2hi  = (u16*)(ws + 207667200);     // compact [65536][256] (hi only)
  float* cbuf = (float*)(ws + 274776064);  // compact fp32 [65536][128]
  u16* WLpk = (u16*)(ws + 308330496);      // 8 x 72 x 4096 u16
  u16* W2pk = (u16*)(ws + 313049088);      // 4 x 72 x 4096
  u16* W1pk = (u16*)(ws + 315408384);      // 4 x 8 x 4096
  u16* W3pk = (u16*)(ws + 315670528);      // 4 x 8 x 4096
  float* PL = (float*)(ws + 315932672);
  float* P1 = PL + 512;
  float* P2 = P1 + 256;
  float* P3 = P2 + 256;

  // zero halos of padded activation planes (YG, HA/HB hi+lo, T1hi)
  hipMemsetAsync(ws, 0, 173056000, stream);

  quant_s2d_kernel<<<131072, 256, 0, stream>>>(input, q, YG);
  s2d_cond_kernel<<<32768, 256, 0, stream>>>(cond, HAhi, HAlo, cbuf);
  build_wpack<9, 0><<<9216, 256, 0, stream>>>(lstm_w, WLpk);
  build_wpack<9, 1><<<4608, 256, 0, stream>>>(w2, W2pk);
  build_wpack<1, 1><<<512, 256, 0, stream>>>(w1, W1pk);
  build_wpack<1, 2><<<512, 256, 0, stream>>>(w3, W3pk);
  make_biases<<<2, 256, 0, stream>>>(lstm_b, b1, b2, b3, PL, P1, P2, P3);

  for (int g = 0; g < 4; ++g) {
    u16* hinhi  = (g & 1) ? HBhi : HAhi;
    u16* hinlo  = (g & 1) ? HBlo : HAlo;
    u16* houthi = (g & 1) ? HAhi : HBhi;
    u16* houtlo = (g & 1) ? HAlo : HBlo;
    const u16* yihi = g ? (YG + (size_t)(g - 1) * P128) : hinhi;  // g=0: dead (skipped)
    const u16* zg = YG + (size_t)g * P128;

    // ConvLSTM 3x3: [yi, h] -> 512 gate cols, fused LSTM update (3-pass precise)
    conv_mfma<9, 512, 0, 1, 1><<<dim3(4, 512), 256, 0, stream>>>(
        yihi, yihi, hinhi, hinlo, 128, 130, 1,
        /*lo0=*/0, /*lo1=*/1, /*skiphalf=*/g ? 0 : 1,
        WLpk, PL, cbuf, houthi, houtlo, 0, 0, nullptr, nullptr, g);
    // w1 1x1: [h, yi] -> 256, lrelu -> t1 (padded, hi only) — single-pass
    conv_mfma<1, 256, 1, 0, 0><<<dim3(2, 512), 256, 0, stream>>>(
        houthi, houthi, yihi, yihi, 128, 130, 1,
        0, 0, /*skiphalf=*/g ? 0 : 2,
        W1pk, P1, nullptr, T1hi, nullptr, 130, 1, nullptr, nullptr, g);
    // w2 3x3: t1 -> 256, lrelu -> t2 (compact, hi only) — single-pass
    conv_mfma<9, 256, 1, 0, 0><<<dim3(2, 512), 256, 0, stream>>>(
        T1hi, T1hi, T1hi + 128, T1hi + 128, 256, 130, 1,
        0, 0, 0,
        W2pk, P2, nullptr, T2hi, nullptr, 128, 0, nullptr, nullptr, g);
    // w3 1x1 + likelihood — single-pass
    conv_mfma<1, 256, 2, 0, 0><<<dim3(2, 512), 256, 0, stream>>>(
        T2hi, T2hi, T2hi + 128, T2hi + 128, 256, 128, 0,
        0, 0, 0,
        W3pk, P3, nullptr, nullptr, nullptr, 0, 0, zg, lik, g);
  }
}

// Round 7
// 2359.219 us; speedup vs baseline: 5.6338x; 1.0757x over previous
//
#include <hip/hip_runtime.h>
#include <math.h>

typedef unsigned short u16;
typedef __attribute__((ext_vector_type(8))) short bf16x8;
typedef __attribute__((ext_vector_type(4))) float f32x4;

#define P128 8652800    // elems of padded 128-ch plane: 4*130*130*128

__device__ __forceinline__ u16 f2bf(float f) {
  unsigned u = __float_as_uint(f);
  unsigned r = u + 0x7fffu + ((u >> 16) & 1u);
  return (u16)(r >> 16);
}
__device__ __forceinline__ float bf2f(u16 h) {
  return __uint_as_float(((unsigned)h) << 16);
}
__device__ __forceinline__ void gl16(const u16* g, const u16* l) {
  __builtin_amdgcn_global_load_lds(
      (const __attribute__((address_space(1))) void*)g,
      (__attribute__((address_space(3))) void*)l, 16, 0, 0);
}

// ---------- quantize + s2d into padded bf16 group planes --------------------
__global__ void quant_s2d_kernel(const float* __restrict__ inp,
                                 float* __restrict__ q,
                                 u16* __restrict__ yghi) {
  int idx = blockIdx.x * 256 + threadIdx.x;   // 33,554,432
  int ww = idx & 255;
  int hh = (idx >> 8) & 255;
  int cc = (idx >> 16) & 127;
  int b  = idx >> 23;
  float v = rintf(inp[idx]);
  q[idx] = v;
  int g = cc >> 5;
  int f = ((cc & 31) << 2) | ((hh & 1) << 1) | (ww & 1);
  int y = hh >> 1, x = ww >> 1;
  int p = (b * 130 + y + 1) * 130 + 1 + x;
  yghi[g * P128 + p * 128 + f] = f2bf(v);   // small integer -> exact
}

// ---------- s2d of condition -> h0 (padded bf16) + c0 (compact fp32) --------
__global__ void s2d_cond_kernel(const float* __restrict__ cond,
                                u16* __restrict__ hhi, float* __restrict__ c0) {
  int idx = blockIdx.x * 256 + threadIdx.x;   // 8,388,608
  int ww = idx & 255;
  int hh = (idx >> 8) & 255;
  int cc = (idx >> 16) & 31;
  int b  = idx >> 21;
  float v = cond[idx];
  int ch = (cc << 2) | ((hh & 1) << 1) | (ww & 1);
  int y = hh >> 1, x = ww >> 1;
  int p = (b * 130 + y + 1) * 130 + 1 + x;
  hhi[p * 128 + ch] = f2bf(v);
  c0[((b * 128 + y) * 128 + x) * 128 + ch] = v;
}

// ---------- weight pack: per (cb*2+wn, slab) wave-fragment layout -----------
// out[(cbwn*NSLAB + slab)][plane(hi/lo)][ni][lane][8]  (4096 u16 per slab blk)
// lane fragment: col = cbwn*64 + ni*16 + (lane&15); k = slab*32 + (lane>>4)*8 + j
// Only the hi plane is consumed (single-pass bf16); lo kept for layout compat.
template <int TAPS, int PERM>
__global__ void build_wpack(const float* __restrict__ w, u16* __restrict__ o) {
  int idx = blockIdx.x * 256 + threadIdx.x;
  int jj = idx & 7, lane = (idx >> 3) & 63, ni = (idx >> 9) & 3, plane = (idx >> 11) & 1;
  int rest = idx >> 12;
  const int NSLAB = TAPS * 8;
  int slab = rest % NSLAB, cbwn = rest / NSLAB;
  int c = cbwn * 64 + ni * 16 + (lane & 15);
  int k = slab * 32 + ((lane >> 4) << 3) + jj;
  int tap = (TAPS == 9) ? (k >> 8) : 0;
  int ci = (TAPS == 9) ? (k & 255) : k;
  int oc;
  if (PERM == 0)      oc = ((c >> 4) & 3) * 128 + (c >> 7) * 32 + ((c >> 6) & 1) * 16 + (c & 15);
  else if (PERM == 2) oc = ((c >> 4) & 1) * 128 + (c >> 7) * 64 + ((c >> 6) & 1) * 32 + ((c >> 5) & 1) * 16 + (c & 15);
  else                oc = c;
  float v = w[((size_t)(oc * 256 + ci)) * TAPS + tap];
  u16 h = f2bf(v);
  o[idx] = plane ? f2bf(v - bf2f(h)) : h;
}

__global__ void make_biases(const float* __restrict__ lb, const float* __restrict__ b1,
                            const float* __restrict__ b2, const float* __restrict__ b3,
                            float* __restrict__ pl, float* __restrict__ p1,
                            float* __restrict__ p2, float* __restrict__ p3) {
  int t = blockIdx.x * 256 + threadIdx.x;     // launch 512
  if (t < 512) {
    int gate = (t >> 4) & 3;
    int f = (t >> 7) * 32 + ((t >> 6) & 1) * 16 + (t & 15);
    pl[t] = lb[gate * 128 + f];
  }
  if (t < 256) {
    p1[t] = b1[t];
    p2[t] = b2[t];
    int m = (t >> 4) & 1;
    int f = (t >> 7) * 64 + ((t >> 6) & 1) * 32 + ((t >> 5) & 1) * 16 + (t & 15);
    p3[t] = b3[m * 128 + f];
  }
}

// ---------- MFMA conv: barrier-free per-wave pipeline, single-pass bf16 -----
// Each wave stages its own 64-pixel A-region into a private LDS segment via
// global_load_lds (per-wave vmcnt; no s_barrier). Prefetch distance 1.
// LDS per-wave segment layout: [kchunk(4)][pixel(64)][8] u16 -> reader lane
// byte addr = mi*1024 + kq*256 + fl*16: uniform bank coverage, conflict-free
// (rounds 2-5 measured 0 conflicts with this pattern). gl16 writes linearly
// (base + lane*16B), so the SOURCE address is lane-swizzled to match:
// lane -> (chunk=lane>>4, pixel=c*16+(lane&15)) per call c.
// vmcnt window protocol: every window between "memory"-clobber asms issues
// exactly 8 vmem ops (A:4 gl16 + W:4 dwordx4) -> vmcnt(8) guarantees the
// PREVIOUS window's A-DMA and W-loads completed. lgkmcnt(0) before re-staging
// a buffer guarantees the wave's own ds_reads of it finished.
// EPI 0: LSTM update (c fp32 in cbuf); EPI 1: lrelu->bf16; EPI 2: likelihood.
template <int TAPS, int NCOL, int EPI>
__global__ __launch_bounds__(256, 3)
void conv_mfma(const u16* __restrict__ a0hi, const u16* __restrict__ a1hi,
               int C, int RS, int PAD, int skiphalf,
               const u16* __restrict__ Wpk, const float* __restrict__ biasP,
               float* __restrict__ c_io,
               u16* __restrict__ ohi, int ORS, int OPAD,
               const u16* __restrict__ zsrc, float* __restrict__ lik, int g) {
  constexpr int NSLAB = TAPS * 8;
  constexpr int NCB = NCOL / 128;
  constexpr int WV = 2048;                    // u16 per wave-buffer segment
  __shared__ __attribute__((aligned(16))) u16 lds[8 * WV];  // 2 bufs x 4 waves x 4KB
  const int tid = threadIdx.x;
  const int lane = tid & 63, wid = tid >> 6;
  const int wm = wid >> 1, wn = wid & 1;
  const int fl = lane & 15, kq = lane >> 4;

  // XCD swizzle: windows of 512 blocks; each XCD gets contiguous y-strips x all cb
  int n = blockIdx.y * NCB + blockIdx.x;
  int w_ = n >> 9, r_ = n & 511;
  int xj = r_ & 7, tt = r_ >> 3;
  const int cb = tt & (NCB - 1);
  const int YL = 64 / NCB;
  int ystrip = w_ * (8 * YL) + xj * YL + (tt / NCB);
  const int b = ystrip >> 7, y = ystrip & 127;

  const int NS = skiphalf ? NSLAB / 2 : NSLAB;
  f32x4 acc[4][4] = {};

  const u16* wbase = Wpk + (size_t)(cb * 2 + wn) * NSLAB * 4096;

  auto mapslab = [&](int si) -> int {
    if (!skiphalf) return si;
    int tap = si >> 2, o = si & 3;
    return tap * 8 + (skiphalf == 1 ? 4 + o : o);
  };
  auto issueA = [&](int si, int buf) {   // 4 gl16 per wave
    int s = mapslab(si);
    int dy = 0, dx = 0;
    if (TAPS == 9) { int tap = s >> 3; dy = tap / 3 - 1; dx = tap % 3 - 1; }
    int ci0 = (s & 7) * 32;
    const u16* ahi = (ci0 < 128) ? a0hi : a1hi;
    int cib = ci0 & 127;
    int origin = (b * RS + y + PAD) * RS + PAD + dy * RS + dx;
    size_t rowb = (size_t)(origin + wm * 64 + fl) * C + cib + kq * 8;
    const u16* lb = &lds[buf * 4 * WV + wid * WV];
#pragma unroll
    for (int c = 0; c < 4; ++c)
      gl16(ahi + rowb + (size_t)(c * 16) * C, lb + c * 512);
  };
  auto issueW = [&](int si, bf16x8* W) {  // 4 coalesced dwordx4 per wave
    int s = mapslab(si);
    const bf16x8* wp = (const bf16x8*)(wbase + (size_t)s * 4096);
#pragma unroll
    for (int i = 0; i < 4; ++i) W[i] = wp[i * 64 + lane];
  };
  auto compute = [&](const bf16x8* W, int buf) {
    const u16* ab = &lds[buf * 4 * WV + wid * WV + kq * 128 + fl * 8];
    bf16x8 Ah[4];
#pragma unroll
    for (int i = 0; i < 4; ++i) Ah[i] = *(const bf16x8*)(ab + i * 512);
    __builtin_amdgcn_s_setprio(1);
#pragma unroll
    for (int mi = 0; mi < 4; ++mi)
#pragma unroll
      for (int ni = 0; ni < 4; ++ni)
        acc[mi][ni] = __builtin_amdgcn_mfma_f32_16x16x32_bf16(Ah[mi], W[ni], acc[mi][ni], 0, 0, 0);
    __builtin_amdgcn_s_setprio(0);
  };

#define LGKM0() asm volatile("s_waitcnt lgkmcnt(0)" ::: "memory")
#define VM8()   asm volatile("s_waitcnt vmcnt(8)" ::: "memory")

  bf16x8 WA[4], WB[4];
  issueA(0, 0);
  issueW(0, WA);
  for (int si = 0; si < NS; si += 2) {   // NS always even
    LGKM0();                             // buf1 ds_reads (prev iter) done
    issueA(si + 1, 1);
    issueW(si + 1, WB);
    VM8();                               // A(si), W(si) landed
    compute(WA, 0);
    if (si + 2 < NS) {
      LGKM0();                           // buf0 ds_reads done
      issueA(si + 2, 0);
      issueW(si + 2, WA);
      VM8();                             // A(si+1), W(si+1) landed
    } else {
      asm volatile("s_waitcnt vmcnt(0)" ::: "memory");
    }
    compute(WB, 1);
  }
#undef LGKM0
#undef VM8

  if (EPI == 0) {
    const int f = cb * 32 + wn * 16 + fl;
    float bi[4];
#pragma unroll
    for (int ni = 0; ni < 4; ++ni) bi[ni] = biasP[cb * 128 + wn * 64 + ni * 16 + fl];
#pragma unroll
    for (int mi = 0; mi < 4; ++mi)
#pragma unroll
      for (int r = 0; r < 4; ++r) {
        int x = wm * 64 + mi * 16 + kq * 4 + r;
        int ci = ((b * 128 + y) * 128 + x) * 128 + f;
        float ig = 1.f / (1.f + expf(-(acc[mi][0][r] + bi[0])));
        float fg = 1.f / (1.f + expf(-(acc[mi][1][r] + bi[1])));
        float og = 1.f / (1.f + expf(-(acc[mi][2][r] + bi[2])));
        float gg = tanhf(acc[mi][3][r] + bi[3]);
        float cn = fg * c_io[ci] + ig * gg;
        c_io[ci] = cn;
        float hv = og * tanhf(cn);
        int hx = ((b * 130 + y + 1) * 130 + 1 + x) * 128 + f;
        ohi[hx] = f2bf(hv);
      }
  } else if (EPI == 1) {
#pragma unroll
    for (int ni = 0; ni < 4; ++ni) {
      int c = cb * 128 + wn * 64 + ni * 16 + fl;
      float bv = biasP[c];
#pragma unroll
      for (int mi = 0; mi < 4; ++mi)
#pragma unroll
        for (int r = 0; r < 4; ++r) {
          int x = wm * 64 + mi * 16 + kq * 4 + r;
          float v = acc[mi][ni][r] + bv;
          v = (v >= 0.f) ? v : 0.01f * v;
          int oi = ((b * ORS + y + OPAD) * ORS + OPAD + x) * 256 + c;
          ohi[oi] = f2bf(v);
        }
    }
  } else {
#pragma unroll
    for (int j = 0; j < 2; ++j) {
      int f = cb * 64 + wn * 32 + j * 16 + fl;
      float bm = biasP[cb * 128 + wn * 64 + j * 32 + fl];
      float bs = biasP[cb * 128 + wn * 64 + j * 32 + 16 + fl];
#pragma unroll
      for (int mi = 0; mi < 4; ++mi)
#pragma unroll
        for (int r = 0; r < 4; ++r) {
          int x = wm * 64 + mi * 16 + kq * 4 + r;
          float mean = acc[mi][2 * j][r] + bm;
          float sc = fmaxf(acc[mi][2 * j + 1][r] + bs, 0.11f);
          float z = bf2f(zsrc[((b * 130 + y + 1) * 130 + 1 + x) * 128 + f]);
          float is = 0.70710678118654752f / sc;
          float up = 0.5f * (1.f + erff((z - mean + 0.5f) * is));
          float lo_ = 0.5f * (1.f + erff((z - mean - 0.5f) * is));
          lik[((b * 512 + g * 128 + f) * 128 + y) * 128 + x] = fmaxf(up - lo_, 1e-9f);
        }
    }
  }
}

// ---------- host launch ------------------------------------------------------
extern "C" void kernel_launch(void* const* d_in, const int* in_sizes, int n_in,
                              void* d_out, int out_size, void* d_ws, size_t ws_size,
                              hipStream_t stream) {
  const float* input  = (const float*)d_in[0];
  const float* cond   = (const float*)d_in[1];
  const float* lstm_w = (const float*)d_in[2];
  const float* lstm_b = (const float*)d_in[3];
  const float* w1 = (const float*)d_in[4];
  const float* b1 = (const float*)d_in[5];
  const float* w2 = (const float*)d_in[6];
  const float* b2 = (const float*)d_in[7];
  const float* w3 = (const float*)d_in[8];
  const float* b3 = (const float*)d_in[9];

  float* q   = (float*)d_out;
  float* lik = q + 33554432;

  char* ws = (char*)d_ws;
  u16* YG    = (u16*)(ws + 0);             // 4 x P128 hi planes
  u16* HAhi  = (u16*)(ws + 69222400);
  u16* HBhi  = (u16*)(ws + 86528000);
  u16* T1hi  = (u16*)(ws + 103833600);     // padded 256-ch plane
  u16* T2hi  = (u16*)(ws + 138444800);     // compact [65536][256]
  float* cbuf = (float*)(ws + 171999232);  // compact fp32 [65536][128]
  u16* WLpk = (u16*)(ws + 205553664);      // 8 x 72 x 4096 u16 (hi+lo planes)
  u16* W2pk = (u16*)(ws + 210272256);      // 4 x 72 x 4096
  u16* W1pk = (u16*)(ws + 212631552);      // 4 x 8 x 4096
  u16* W3pk = (u16*)(ws + 212893696);      // 4 x 8 x 4096
  float* PL = (float*)(ws + 213155840);
  float* P1 = PL + 512;
  float* P2 = P1 + 256;
  float* P3 = P2 + 256;

  // zero halos of padded activation planes (YG, HAhi, HBhi, T1hi)
  hipMemsetAsync(ws, 0, 138444800, stream);

  quant_s2d_kernel<<<131072, 256, 0, stream>>>(input, q, YG);
  s2d_cond_kernel<<<32768, 256, 0, stream>>>(cond, HAhi, cbuf);
  build_wpack<9, 0><<<9216, 256, 0, stream>>>(lstm_w, WLpk);
  build_wpack<9, 1><<<4608, 256, 0, stream>>>(w2, W2pk);
  build_wpack<1, 1><<<512, 256, 0, stream>>>(w1, W1pk);
  build_wpack<1, 2><<<512, 256, 0, stream>>>(w3, W3pk);
  make_biases<<<2, 256, 0, stream>>>(lstm_b, b1, b2, b3, PL, P1, P2, P3);

  for (int g = 0; g < 4; ++g) {
    u16* hinhi  = (g & 1) ? HBhi : HAhi;
    u16* houthi = (g & 1) ? HAhi : HBhi;
    const u16* yihi = g ? (YG + (size_t)(g - 1) * P128) : hinhi;  // g=0: dead (skipped)
    const u16* zg = YG + (size_t)g * P128;

    // ConvLSTM 3x3: [yi, h] -> 512 gate cols, fused LSTM update
    conv_mfma<9, 512, 0><<<dim3(4, 512), 256, 0, stream>>>(
        yihi, hinhi, 128, 130, 1, /*skiphalf=*/g ? 0 : 1,
        WLpk, PL, cbuf, houthi, 0, 0, nullptr, nullptr, g);
    // w1 1x1: [h, yi] -> 256, lrelu -> t1 (padded)
    conv_mfma<1, 256, 1><<<dim3(2, 512), 256, 0, stream>>>(
        houthi, yihi, 128, 130, 1, /*skiphalf=*/g ? 0 : 2,
        W1pk, P1, nullptr, T1hi, 130, 1, nullptr, nullptr, g);
    // w2 3x3: t1 -> 256, lrelu -> t2 (compact)
    conv_mfma<9, 256, 1><<<dim3(2, 512), 256, 0, stream>>>(
        T1hi, T1hi + 128, 256, 130, 1, 0,
        W2pk, P2, nullptr, T2hi, 128, 0, nullptr, nullptr, g);
    // w3 1x1 + likelihood
    conv_mfma<1, 256, 2><<<dim3(2, 512), 256, 0, stream>>>(
        T2hi, T2hi + 128, 256, 128, 0, 0,
        W3pk, P3, nullptr, nullptr, 0, 0, zg, lik, g);
  }
}

// Round 8
// 1341.321 us; speedup vs baseline: 9.9092x; 1.7589x over previous
//
#include <hip/hip_runtime.h>
#include <math.h>

typedef unsigned short u16;
typedef __attribute__((ext_vector_type(8))) short bf16x8;
typedef __attribute__((ext_vector_type(4))) float f32x4;

#define PSUB 2163200   // elems per padded 32-ch sub-plane: 4*130*130*32
#define TSUB 2097152   // elems per compact 32-ch sub-plane: 4*128*128*32

__device__ __forceinline__ u16 f2bf(float f) {
  unsigned u = __float_as_uint(f);
  unsigned r = u + 0x7fffu + ((u >> 16) & 1u);
  return (u16)(r >> 16);
}
__device__ __forceinline__ float bf2f(u16 h) {
  return __uint_as_float(((unsigned)h) << 16);
}
__device__ __forceinline__ void gl16(const u16* g, const u16* l) {
  __builtin_amdgcn_global_load_lds(
      (const __attribute__((address_space(1))) void*)g,
      (__attribute__((address_space(3))) void*)l, 16, 0, 0);
}

// ---------- quantize + s2d into padded bf16 group sub-planes ----------------
__global__ void quant_s2d_kernel(const float* __restrict__ inp,
                                 float* __restrict__ q,
                                 u16* __restrict__ yghi) {
  int idx = blockIdx.x * 256 + threadIdx.x;   // 33,554,432
  int ww = idx & 255;
  int hh = (idx >> 8) & 255;
  int cc = (idx >> 16) & 127;
  int b  = idx >> 23;
  float v = rintf(inp[idx]);
  q[idx] = v;
  int g = cc >> 5;
  int f = ((cc & 31) << 2) | ((hh & 1) << 1) | (ww & 1);
  int y = hh >> 1, x = ww >> 1;
  int p = (b * 130 + y + 1) * 130 + 1 + x;
  yghi[(size_t)g * 4 * PSUB + (size_t)(f >> 5) * PSUB + (size_t)p * 32 + (f & 31)] = f2bf(v);
}

// ---------- s2d of condition -> h0 (padded sub-planes) + c0 (compact fp32) --
__global__ void s2d_cond_kernel(const float* __restrict__ cond,
                                u16* __restrict__ hhi, float* __restrict__ c0) {
  int idx = blockIdx.x * 256 + threadIdx.x;   // 8,388,608
  int ww = idx & 255;
  int hh = (idx >> 8) & 255;
  int cc = (idx >> 16) & 31;
  int b  = idx >> 21;
  float v = cond[idx];
  int ch = (cc << 2) | ((hh & 1) << 1) | (ww & 1);
  int y = hh >> 1, x = ww >> 1;
  int p = (b * 130 + y + 1) * 130 + 1 + x;
  hhi[(size_t)(ch >> 5) * PSUB + (size_t)p * 32 + (ch & 31)] = f2bf(v);
  c0[((size_t)(b * 128 + y) * 128 + x) * 128 + ch] = v;
}

// ---------- weight pack: per (cb, slab) block layout ------------------------
// Wpk[(cb*NSLAB + slab)*4096 + wn*2048 + ni*512 + lane*8 + jj]
// col c = cb*128 + wn*64 + ni*16 + (lane&15); k = slab*32 + (lane>>4)*8 + jj
// PERM 0: LSTM gate perm; 1: identity; 2: w3 mean/scale perm
template <int TAPS, int PERM>
__global__ void build_wpack(const float* __restrict__ w, u16* __restrict__ o) {
  int idx = blockIdx.x * 256 + threadIdx.x;
  int jj = idx & 7, lane = (idx >> 3) & 63, ni = (idx >> 9) & 3, wn = (idx >> 11) & 1;
  int rest = idx >> 12;
  const int NSLAB = TAPS * 8;
  int slab = rest % NSLAB, cb = rest / NSLAB;
  int c = cb * 128 + wn * 64 + ni * 16 + (lane & 15);
  int k = slab * 32 + ((lane >> 4) << 3) + jj;
  int tap = (TAPS == 9) ? (k >> 8) : 0;
  int ci = (TAPS == 9) ? (k & 255) : k;
  int oc;
  if (PERM == 0)      oc = ((c >> 4) & 3) * 128 + (c >> 7) * 32 + ((c >> 6) & 1) * 16 + (c & 15);
  else if (PERM == 2) oc = ((c >> 4) & 1) * 128 + (c >> 7) * 64 + ((c >> 6) & 1) * 32 + ((c >> 5) & 1) * 16 + (c & 15);
  else                oc = c;
  float v = w[((size_t)(oc * 256 + ci)) * TAPS + tap];
  o[idx] = f2bf(v);
}

__global__ void make_biases(const float* __restrict__ lb, const float* __restrict__ b1,
                            const float* __restrict__ b2, const float* __restrict__ b3,
                            float* __restrict__ pl, float* __restrict__ p1,
                            float* __restrict__ p2, float* __restrict__ p3) {
  int t = blockIdx.x * 256 + threadIdx.x;     // launch 512
  if (t < 512) {
    int gate = (t >> 4) & 3;
    int f = (t >> 7) * 32 + ((t >> 6) & 1) * 16 + (t & 15);
    pl[t] = lb[gate * 128 + f];
  }
  if (t < 256) {
    p1[t] = b1[t];
    p2[t] = b2[t];
    int m = (t >> 4) & 1;
    int f = (t >> 7) * 64 + ((t >> 6) & 1) * 32 + ((t >> 5) & 1) * 16 + (t & 15);
    p3[t] = b3[m * 128 + f];
  }
}

// ---------- MFMA conv: cooperative staging + counted vmcnt across barriers --
// Block = 128-px row x 128 cols, 4 waves (wm x wn = 2x2), 16 MFMA/slab/wave.
// Activations are chunk-32 sub-planes [pix][32]: a slab (chunk, tap) of 128 px
// is ONE contiguous 8 KB region -> staged block-wide by 8x1024B gl16 (2/wave).
// W pre-packed per (cb, slab) as contiguous 8 KB -> 8x1024B gl16 (2/wave).
// Loop: stage(s+1) [4 ops/wave] -> s_waitcnt vmcnt(4) (stage(s) landed,
// stage(s+1) stays IN FLIGHT across the barrier - T4) -> s_barrier ->
// ds_read frags (contiguous-permuted 1024B, conflict-free) + MFMA ->
// s_barrier (buffer-reuse guard). No vmcnt(0) until the last slab.
// EPI 0: LSTM update; EPI 1: lrelu -> sub-planes; EPI 2: likelihood.
template <int TAPS, int NCOL, int EPI>
__global__ __launch_bounds__(256, 4)
void conv_mfma(const u16* __restrict__ a0, const u16* __restrict__ a1,
               int RS, int PAD, int skiphalf,
               const u16* __restrict__ Wpk, const float* __restrict__ biasP,
               float* __restrict__ c_io,
               u16* __restrict__ ohi, size_t OSUB, int ORS, int OPAD,
               const u16* __restrict__ zsrc, float* __restrict__ lik, int g) {
  constexpr int NSLAB = TAPS * 8;
  constexpr int NCB = NCOL / 128;
  __shared__ __attribute__((aligned(16))) u16 lds[16384];  // A dbuf 2x4K elems, W dbuf 2x4K elems
  const int tid = threadIdx.x;
  const int lane = tid & 63, wid = tid >> 6;
  const int wm = wid >> 1, wn = wid & 1;
  const int fl = lane & 15, kq = lane >> 4;

  // XCD swizzle: windows of 512 blocks; each XCD gets contiguous y-strips x all cb
  int n = blockIdx.y * NCB + blockIdx.x;
  int w_ = n >> 9, r_ = n & 511;
  int xj = r_ & 7, tt = r_ >> 3;
  const int cb = tt & (NCB - 1);
  const int YL = 64 / NCB;
  int ystrip = w_ * (8 * YL) + xj * YL + (tt / NCB);
  const int b = ystrip >> 7, y = ystrip & 127;

  const int NS = skiphalf ? NSLAB / 2 : NSLAB;
  f32x4 acc[4][4] = {};

  auto mapslab = [&](int si) -> int {
    if (!skiphalf) return si;
    int tap = si >> 2, o = si & 3;
    return tap * 8 + (skiphalf == 1 ? 4 + o : o);
  };
  auto stage = [&](int si, int buf) {   // 4 gl16 per wave (2 A + 2 W), all contiguous
    int s = mapslab(si);
    int dy = 0, dx = 0;
    if (TAPS == 9) { int tap = s >> 3; dy = tap / 3 - 1; dx = tap % 3 - 1; }
    int cc = s & 7;
    const u16* ap = ((cc < 4) ? a0 : a1) + (size_t)(cc & 3) * ((TAPS == 1 && EPI == 2) ? (size_t)TSUB : (size_t)PSUB);
    // NOTE: sub-plane stride: padded inputs use PSUB; w3's compact T2 uses TSUB.
    int origin = (b * RS + y + PAD) * RS + PAD + dy * RS + dx;
    const u16* abase = ap + (size_t)origin * 32;
    const u16* wbase = Wpk + ((size_t)(cb * NSLAB + s)) * 4096;
#pragma unroll
    for (int t = 0; t < 2; ++t) {
      int j = wid * 2 + t;
      gl16(abase + j * 512 + lane * 8, &lds[buf * 4096 + j * 512]);
    }
#pragma unroll
    for (int t = 0; t < 2; ++t) {
      int j = wid * 2 + t;
      gl16(wbase + j * 512 + lane * 8, &lds[8192 + buf * 4096 + j * 512]);
    }
  };
  auto compute = [&](int buf) {
    bf16x8 Ah[4], Wf[4];
#pragma unroll
    for (int i = 0; i < 4; ++i)
      Ah[i] = *(const bf16x8*)&lds[buf * 4096 + (wm * 64 + i * 16 + fl) * 32 + kq * 8];
#pragma unroll
    for (int i = 0; i < 4; ++i)
      Wf[i] = *(const bf16x8*)&lds[8192 + buf * 4096 + wn * 2048 + i * 512 + lane * 8];
    __builtin_amdgcn_s_setprio(1);
#pragma unroll
    for (int mi = 0; mi < 4; ++mi)
#pragma unroll
      for (int ni = 0; ni < 4; ++ni)
        acc[mi][ni] = __builtin_amdgcn_mfma_f32_16x16x32_bf16(Ah[mi], Wf[ni], acc[mi][ni], 0, 0, 0);
    __builtin_amdgcn_s_setprio(0);
  };

  stage(0, 0);
  for (int s = 0; s < NS; ++s) {
    if (s + 1 < NS) {
      stage(s + 1, (s + 1) & 1);
      asm volatile("s_waitcnt vmcnt(4)" ::: "memory");   // stage(s) landed; stage(s+1) in flight
    } else {
      asm volatile("s_waitcnt vmcnt(0)" ::: "memory");
    }
    __builtin_amdgcn_s_barrier();       // all waves' stage(s) visible
    compute(s & 1);
    __builtin_amdgcn_s_barrier();       // reads of buf(s&1) done before restage
  }

  if (EPI == 0) {
    const int f = cb * 32 + wn * 16 + fl;
    float bi[4];
#pragma unroll
    for (int ni = 0; ni < 4; ++ni) bi[ni] = biasP[cb * 128 + wn * 64 + ni * 16 + fl];
#pragma unroll
    for (int mi = 0; mi < 4; ++mi)
#pragma unroll
      for (int r = 0; r < 4; ++r) {
        int x = wm * 64 + mi * 16 + kq * 4 + r;
        size_t ci = ((size_t)(b * 128 + y) * 128 + x) * 128 + f;
        float ig = 1.f / (1.f + expf(-(acc[mi][0][r] + bi[0])));
        float fg = 1.f / (1.f + expf(-(acc[mi][1][r] + bi[1])));
        float og = 1.f / (1.f + expf(-(acc[mi][2][r] + bi[2])));
        float gg = tanhf(acc[mi][3][r] + bi[3]);
        float cn = fg * c_io[ci] + ig * gg;
        c_io[ci] = cn;
        float hv = og * tanhf(cn);
        size_t hx = (size_t)((b * 130 + y + 1) * 130 + 1 + x);
        ohi[(size_t)(f >> 5) * PSUB + hx * 32 + (f & 31)] = f2bf(hv);
      }
  } else if (EPI == 1) {
#pragma unroll
    for (int ni = 0; ni < 4; ++ni) {
      int c = cb * 128 + wn * 64 + ni * 16 + fl;
      float bv = biasP[c];
#pragma unroll
      for (int mi = 0; mi < 4; ++mi)
#pragma unroll
        for (int r = 0; r < 4; ++r) {
          int x = wm * 64 + mi * 16 + kq * 4 + r;
          float v = acc[mi][ni][r] + bv;
          v = (v >= 0.f) ? v : 0.01f * v;
          size_t op = (size_t)((b * ORS + y + OPAD) * ORS + OPAD + x);
          ohi[(size_t)(c >> 5) * OSUB + op * 32 + (c & 31)] = f2bf(v);
        }
    }
  } else {
#pragma unroll
    for (int j = 0; j < 2; ++j) {
      int f = cb * 64 + wn * 32 + j * 16 + fl;
      float bm = biasP[cb * 128 + wn * 64 + j * 32 + fl];
      float bs = biasP[cb * 128 + wn * 64 + j * 32 + 16 + fl];
#pragma unroll
      for (int mi = 0; mi < 4; ++mi)
#pragma unroll
        for (int r = 0; r < 4; ++r) {
          int x = wm * 64 + mi * 16 + kq * 4 + r;
          float mean = acc[mi][2 * j][r] + bm;
          float sc = fmaxf(acc[mi][2 * j + 1][r] + bs, 0.11f);
          size_t zp = (size_t)((b * 130 + y + 1) * 130 + 1 + x);
          float z = bf2f(zsrc[(size_t)(f >> 5) * PSUB + zp * 32 + (f & 31)]);
          float is = 0.70710678118654752f / sc;
          float up = 0.5f * (1.f + erff((z - mean + 0.5f) * is));
          float lo_ = 0.5f * (1.f + erff((z - mean - 0.5f) * is));
          lik[((size_t)(b * 512 + g * 128 + f) * 128 + y) * 128 + x] = fmaxf(up - lo_, 1e-9f);
        }
    }
  }
}

// ---------- host launch ------------------------------------------------------
extern "C" void kernel_launch(void* const* d_in, const int* in_sizes, int n_in,
                              void* d_out, int out_size, void* d_ws, size_t ws_size,
                              hipStream_t stream) {
  const float* input  = (const float*)d_in[0];
  const float* cond   = (const float*)d_in[1];
  const float* lstm_w = (const float*)d_in[2];
  const float* lstm_b = (const float*)d_in[3];
  const float* w1 = (const float*)d_in[4];
  const float* b1 = (const float*)d_in[5];
  const float* w2 = (const float*)d_in[6];
  const float* b2 = (const float*)d_in[7];
  const float* w3 = (const float*)d_in[8];
  const float* b3 = (const float*)d_in[9];

  float* q   = (float*)d_out;
  float* lik = q + 33554432;

  char* ws = (char*)d_ws;
  u16* YG    = (u16*)(ws + 0);             // 4 groups x 4 sub-planes (padded)
  u16* HAhi  = (u16*)(ws + 69222400);      // 4 sub-planes
  u16* HBhi  = (u16*)(ws + 86528000);
  u16* T1hi  = (u16*)(ws + 103833600);     // 8 sub-planes padded
  u16* T2hi  = (u16*)(ws + 138444800);     // 8 sub-planes compact
  float* cbuf = (float*)(ws + 171999232);  // compact fp32 [65536][128]
  u16* WLpk = (u16*)(ws + 205553664);      // 4 x 72 x 4096 u16
  u16* W2pk = (u16*)(ws + 207912960);      // 2 x 72 x 4096
  u16* W1pk = (u16*)(ws + 209092608);      // 2 x 8 x 4096
  u16* W3pk = (u16*)(ws + 209223680);      // 2 x 8 x 4096
  float* PL = (float*)(ws + 209354752);
  float* P1 = PL + 512;
  float* P2 = P1 + 256;
  float* P3 = P2 + 256;

  // zero halos of padded activation planes (YG, HAhi, HBhi, T1hi)
  hipMemsetAsync(ws, 0, 138444800, stream);

  quant_s2d_kernel<<<131072, 256, 0, stream>>>(input, q, YG);
  s2d_cond_kernel<<<32768, 256, 0, stream>>>(cond, HAhi, cbuf);
  build_wpack<9, 0><<<4608, 256, 0, stream>>>(lstm_w, WLpk);
  build_wpack<9, 1><<<2304, 256, 0, stream>>>(w2, W2pk);
  build_wpack<1, 1><<<256, 256, 0, stream>>>(w1, W1pk);
  build_wpack<1, 2><<<256, 256, 0, stream>>>(w3, W3pk);
  make_biases<<<2, 256, 0, stream>>>(lstm_b, b1, b2, b3, PL, P1, P2, P3);

  for (int g = 0; g < 4; ++g) {
    u16* hinhi  = (g & 1) ? HBhi : HAhi;
    u16* houthi = (g & 1) ? HAhi : HBhi;
    const u16* yihi = g ? (YG + (size_t)(g - 1) * 4 * PSUB) : hinhi;  // g=0: dead (skipped)
    const u16* zg = YG + (size_t)g * 4 * PSUB;

    // ConvLSTM 3x3: [yi, h] -> 512 gate cols, fused LSTM update
    conv_mfma<9, 512, 0><<<dim3(4, 512), 256, 0, stream>>>(
        yihi, hinhi, 130, 1, /*skiphalf=*/g ? 0 : 1,
        WLpk, PL, cbuf, houthi, PSUB, 0, 0, nullptr, nullptr, g);
    // w1 1x1: [h, yi] -> 256, lrelu -> t1 (padded)
    conv_mfma<1, 256, 1><<<dim3(2, 512), 256, 0, stream>>>(
        houthi, yihi, 130, 1, /*skiphalf=*/g ? 0 : 2,
        W1pk, P1, nullptr, T1hi, PSUB, 130, 1, nullptr, nullptr, g);
    // w2 3x3: t1 -> 256, lrelu -> t2 (compact)
    conv_mfma<9, 256, 1><<<dim3(2, 512), 256, 0, stream>>>(
        T1hi, T1hi + (size_t)4 * PSUB, 130, 1, 0,
        W2pk, P2, nullptr, T2hi, TSUB, 128, 0, nullptr, nullptr, g);
    // w3 1x1 + likelihood (compact input -> stride TSUB via EPI==2 special-case)
    conv_mfma<1, 256, 2><<<dim3(2, 512), 256, 0, stream>>>(
        T2hi, T2hi + (size_t)4 * TSUB, 128, 0, 0,
        W3pk, P3, nullptr, nullptr, 0, 0, 0, zg, lik, g);
  }
}